// Round 1
// baseline (2090.252 us; speedup 1.0000x reference)
//
#include <hip/hip_runtime.h>

#define DECAY 0.99f
#define BETA 0.25f
#define EPSV 1e-5f

// Problem constants
// z: [32, 256, 32, 32] fp32 ; embedding: [1024, 256] ; N = 32*32*32 = 32768
#define Bb 32
#define Dd 256
#define Kk 1024
#define Nn 32768
#define ZELEM 8388608   // 32*256*32*32

// ---------------------------------------------------------------------------
// Kernel 1: ||e_k||^2 per codebook row. One wave per row.
__global__ void esq_kernel(const float* __restrict__ emb, float* __restrict__ esq) {
    const int k = blockIdx.x;
    const int lane = threadIdx.x;          // 64 lanes
    const float4 v = ((const float4*)(emb + (size_t)k * Dd))[lane]; // 64 float4 = 256 floats
    float s = v.x * v.x + v.y * v.y + v.z * v.z + v.w * v.w;
    #pragma unroll
    for (int off = 32; off > 0; off >>= 1) s += __shfl_down(s, off);
    if (lane == 0) esq[k] = s;
}

// ---------------------------------------------------------------------------
// Kernel 2: distance + argmin. Block = 256 threads handles 64 points x all K.
// score = e_sq[k] - 2 * z.e  (||z||^2 dropped: row-constant for argmin)
__global__ __launch_bounds__(256) void dist_argmin_kernel(
        const float* __restrict__ z, const float* __restrict__ emb,
        const float* __restrict__ esq, int* __restrict__ idx_i,
        float* __restrict__ idx_f) {
    __shared__ float zs[32][64];     // [d][point]
    __shared__ float es[32][68];     // [d][code], padded stride 68 for aligned b128
    __shared__ float red_val[64][16];
    __shared__ int   red_idx[64][16];

    const int t  = threadIdx.x;
    const int tx = t & 15;           // point group: points tx*4 .. tx*4+3
    const int ty = t >> 4;           // code group:  codes  ty*4 .. ty*4+3 (per K-tile)
    const int n0 = blockIdx.x * 64;
    const int b   = n0 >> 10;
    const int rem = n0 & 1023;
    const size_t zbase = (size_t)b * (Dd * 1024) + rem;

    float best[4];
    int   bidx[4];
    #pragma unroll
    for (int a = 0; a < 4; ++a) { best[a] = 3.4e38f; bidx[a] = 0; }

    for (int kt = 0; kt < Kk / 64; ++kt) {
        const int k0 = kt * 64;
        float acc[4][4] = {};
        float esql[4];
        #pragma unroll
        for (int q = 0; q < 4; ++q) esql[q] = esq[k0 + ty * 4 + q];

        for (int dc = 0; dc < Dd / 32; ++dc) {
            const int d0 = dc * 32;
            __syncthreads();
            // stage z tile: [32 d][64 points], float4 over points
            {
                const int i4 = (t & 15) * 4;
                const int dl = t >> 4;     // 0..15, 2 passes
                #pragma unroll
                for (int p = 0; p < 2; ++p) {
                    const int d = dl + p * 16;
                    const float4 v = *(const float4*)(z + zbase + (size_t)(d0 + d) * 1024 + i4);
                    *(float4*)&zs[d][i4] = v;
                }
            }
            // stage e tile transposed: [32 d][64 codes]
            {
                const int dl4 = (t & 7) * 4;
                const int kk  = t >> 3;    // 0..31, 2 passes
                #pragma unroll
                for (int p = 0; p < 2; ++p) {
                    const int k = kk + p * 32;
                    const float4 v = *(const float4*)(emb + (size_t)(k0 + k) * Dd + d0 + dl4);
                    es[dl4 + 0][k] = v.x;
                    es[dl4 + 1][k] = v.y;
                    es[dl4 + 2][k] = v.z;
                    es[dl4 + 3][k] = v.w;
                }
            }
            __syncthreads();
            #pragma unroll
            for (int dt = 0; dt < 32; ++dt) {
                const float4 zv = *(const float4*)&zs[dt][tx * 4];
                const float4 ev = *(const float4*)&es[dt][ty * 4];
                const float za[4] = {zv.x, zv.y, zv.z, zv.w};
                const float eb[4] = {ev.x, ev.y, ev.z, ev.w};
                #pragma unroll
                for (int a = 0; a < 4; ++a)
                    #pragma unroll
                    for (int q = 0; q < 4; ++q)
                        acc[a][q] = fmaf(za[a], eb[q], acc[a][q]);
            }
        }
        // fold this K-tile into running argmin
        #pragma unroll
        for (int a = 0; a < 4; ++a) {
            #pragma unroll
            for (int q = 0; q < 4; ++q) {
                const float val = esql[q] - 2.0f * acc[a][q];
                const int ki = k0 + ty * 4 + q;
                if (val < best[a] || (val == best[a] && ki < bidx[a])) {
                    best[a] = val; bidx[a] = ki;
                }
            }
        }
    }

    __syncthreads();
    #pragma unroll
    for (int a = 0; a < 4; ++a) {
        red_val[tx * 4 + a][ty] = best[a];
        red_idx[tx * 4 + a][ty] = bidx[a];
    }
    __syncthreads();
    if (t < 64) {
        float bv = red_val[t][0];
        int   bi = red_idx[t][0];
        #pragma unroll
        for (int y = 1; y < 16; ++y) {
            const float v = red_val[t][y];
            const int   i2 = red_idx[t][y];
            if (v < bv || (v == bv && i2 < bi)) { bv = v; bi = i2; }
        }
        idx_i[n0 + t] = bi;
        idx_f[n0 + t] = (float)bi;
    }
}

// ---------------------------------------------------------------------------
// Kernel 3: gather z_q, scatter dw/counts (atomics), accumulate loss.
// One thread per z element, tid maps directly to [B,C,H,W] layout.
__global__ __launch_bounds__(256) void scatter_kernel(
        const float* __restrict__ z, const float* __restrict__ emb,
        const int* __restrict__ idx, float* __restrict__ zq_out,
        float* __restrict__ dw, float* __restrict__ counts,
        float* __restrict__ loss_acc) {
    const int tid = blockIdx.x * 256 + threadIdx.x;
    const int c = (tid >> 10) & 255;
    const int bidx_ = tid >> 18;
    const int n = bidx_ * 1024 + (tid & 1023);
    const int j = idx[n];
    const float e  = emb[(size_t)j * Dd + c];
    const float zv = z[tid];
    zq_out[tid] = e;
    atomicAdd(&dw[(size_t)j * Dd + c], zv);
    if (c == 0) atomicAdd(&counts[j], 1.0f);
    const float diff = e - zv;
    float s = diff * diff;
    #pragma unroll
    for (int off = 32; off > 0; off >>= 1) s += __shfl_down(s, off);
    if ((threadIdx.x & 63) == 0) atomicAdd(loss_acc, s);
}

// ---------------------------------------------------------------------------
// Kernel 4: cluster-size EMA + Laplace smoothing + loss finalize. 1 block.
__global__ void finalize1_kernel(const float* __restrict__ ema_cs,
                                 const float* __restrict__ counts,
                                 const float* __restrict__ loss_acc,
                                 float* __restrict__ cs_out,
                                 float* __restrict__ cs_ws,
                                 float* __restrict__ loss_out) {
    __shared__ float red[1024];
    const int k = threadIdx.x;
    const float csr = ema_cs[k] * DECAY + (1.0f - DECAY) * counts[k];
    red[k] = csr;
    __syncthreads();
    for (int s = 512; s > 0; s >>= 1) {
        if (k < s) red[k] += red[k + s];
        __syncthreads();
    }
    const float nsum = red[0];
    const float cs = (csr + EPSV) / (nsum + (float)Kk * EPSV) * nsum;
    cs_out[k] = cs;
    cs_ws[k] = cs;
    if (k == 0) loss_out[0] = BETA * loss_acc[0] / (float)ZELEM;
}

// ---------------------------------------------------------------------------
// Kernel 5: new_ema_w and new_embedding (elementwise over K*D).
__global__ __launch_bounds__(256) void finalize2_kernel(
        const float* __restrict__ ema_w, const float* __restrict__ dw,
        const float* __restrict__ cs_ws,
        float* __restrict__ new_emb_out, float* __restrict__ new_ema_w_out) {
    const int i = blockIdx.x * 256 + threadIdx.x;
    const float nw = ema_w[i] * DECAY + (1.0f - DECAY) * dw[i];
    const float cs = cs_ws[i >> 8];
    new_ema_w_out[i] = nw;
    new_emb_out[i]   = nw / cs;
}

// ---------------------------------------------------------------------------
extern "C" void kernel_launch(void* const* d_in, const int* in_sizes, int n_in,
                              void* d_out, int out_size, void* d_ws, size_t ws_size,
                              hipStream_t stream) {
    const float* z      = (const float*)d_in[0];
    const float* emb    = (const float*)d_in[1];
    const float* ema_cs = (const float*)d_in[2];
    const float* ema_w  = (const float*)d_in[3];

    float* out = (float*)d_out;
    float* zq_out        = out;                 // 8388608
    float* idx_out_f     = out + 8388608;       // 32768
    float* loss_out      = out + 8421376;       // 1
    float* new_emb_out   = out + 8421377;       // 262144
    float* cs_out        = out + 8683521;       // 1024
    float* new_ema_w_out = out + 8684545;       // 262144

    float* wsf    = (float*)d_ws;
    int*   idx_i  = (int*)d_ws;                 // 32768 ints
    float* counts = wsf + 32768;                // 1024
    float* cs_ws  = wsf + 33792;                // 1024
    float* loss_a = wsf + 34816;                // 1 (+pad)
    float* esq    = wsf + 35840;                // 1024
    float* dw     = wsf + 36864;                // 262144

    // zero counts / cs_ws / loss / esq / dw in one stream-ordered memset
    hipMemsetAsync(counts, 0, (size_t)(36864 + 262144 - 32768) * sizeof(float), stream);

    esq_kernel<<<Kk, 64, 0, stream>>>(emb, esq);
    dist_argmin_kernel<<<Nn / 64, 256, 0, stream>>>(z, emb, esq, idx_i, idx_out_f);
    scatter_kernel<<<ZELEM / 256, 256, 0, stream>>>(z, emb, idx_i, zq_out, dw, counts, loss_a);
    finalize1_kernel<<<1, 1024, 0, stream>>>(ema_cs, counts, loss_a, cs_out, cs_ws, loss_out);
    finalize2_kernel<<<Kk * Dd / 256, 256, 0, stream>>>(ema_w, dw, cs_ws, new_emb_out, new_ema_w_out);
}

// Round 2
// 767.999 us; speedup vs baseline: 2.7217x; 2.7217x over previous
//
#include <hip/hip_runtime.h>

#define DECAY 0.99f
#define BETA 0.25f
#define EPSV 1e-5f

// z: [32, 256, 32, 32] fp32 ; embedding: [1024, 256] ; N = 32*32*32 = 32768
#define Dd 256
#define Kk 1024
#define Nn 32768
#define ZELEM 8388608   // 32*256*32*32

// ---------------------------------------------------------------------------
// Kernel 1: ||e_k||^2 per codebook row. One wave per row.
__global__ void esq_kernel(const float* __restrict__ emb, float* __restrict__ esq) {
    const int k = blockIdx.x;
    const int lane = threadIdx.x;          // 64 lanes
    const float4 v = ((const float4*)(emb + (size_t)k * Dd))[lane];
    float s = v.x * v.x + v.y * v.y + v.z * v.z + v.w * v.w;
    #pragma unroll
    for (int off = 32; off > 0; off >>= 1) s += __shfl_down(s, off);
    if (lane == 0) esq[k] = s;
}

// ---------------------------------------------------------------------------
// Kernel 2: distance + argmin. Block = 256 threads handles 64 points x all K.
__global__ __launch_bounds__(256) void dist_argmin_kernel(
        const float* __restrict__ z, const float* __restrict__ emb,
        const float* __restrict__ esq, int* __restrict__ idx_i,
        float* __restrict__ idx_f) {
    __shared__ float zs[32][64];
    __shared__ float es[32][68];
    __shared__ float red_val[64][16];
    __shared__ int   red_idx[64][16];

    const int t  = threadIdx.x;
    const int tx = t & 15;
    const int ty = t >> 4;
    const int n0 = blockIdx.x * 64;
    const int b   = n0 >> 10;
    const int rem = n0 & 1023;
    const size_t zbase = (size_t)b * (Dd * 1024) + rem;

    float best[4];
    int   bidx[4];
    #pragma unroll
    for (int a = 0; a < 4; ++a) { best[a] = 3.4e38f; bidx[a] = 0; }

    for (int kt = 0; kt < Kk / 64; ++kt) {
        const int k0 = kt * 64;
        float acc[4][4] = {};
        float esql[4];
        #pragma unroll
        for (int q = 0; q < 4; ++q) esql[q] = esq[k0 + ty * 4 + q];

        for (int dc = 0; dc < Dd / 32; ++dc) {
            const int d0 = dc * 32;
            __syncthreads();
            {
                const int i4 = (t & 15) * 4;
                const int dl = t >> 4;
                #pragma unroll
                for (int p = 0; p < 2; ++p) {
                    const int d = dl + p * 16;
                    const float4 v = *(const float4*)(z + zbase + (size_t)(d0 + d) * 1024 + i4);
                    *(float4*)&zs[d][i4] = v;
                }
            }
            {
                const int dl4 = (t & 7) * 4;
                const int kk  = t >> 3;
                #pragma unroll
                for (int p = 0; p < 2; ++p) {
                    const int k = kk + p * 32;
                    const float4 v = *(const float4*)(emb + (size_t)(k0 + k) * Dd + d0 + dl4);
                    es[dl4 + 0][k] = v.x;
                    es[dl4 + 1][k] = v.y;
                    es[dl4 + 2][k] = v.z;
                    es[dl4 + 3][k] = v.w;
                }
            }
            __syncthreads();
            #pragma unroll
            for (int dt = 0; dt < 32; ++dt) {
                const float4 zv = *(const float4*)&zs[dt][tx * 4];
                const float4 ev = *(const float4*)&es[dt][ty * 4];
                const float za[4] = {zv.x, zv.y, zv.z, zv.w};
                const float eb[4] = {ev.x, ev.y, ev.z, ev.w};
                #pragma unroll
                for (int a = 0; a < 4; ++a)
                    #pragma unroll
                    for (int q = 0; q < 4; ++q)
                        acc[a][q] = fmaf(za[a], eb[q], acc[a][q]);
            }
        }
        #pragma unroll
        for (int a = 0; a < 4; ++a) {
            #pragma unroll
            for (int q = 0; q < 4; ++q) {
                const float val = esql[q] - 2.0f * acc[a][q];
                const int ki = k0 + ty * 4 + q;
                if (val < best[a] || (val == best[a] && ki < bidx[a])) {
                    best[a] = val; bidx[a] = ki;
                }
            }
        }
    }

    __syncthreads();
    #pragma unroll
    for (int a = 0; a < 4; ++a) {
        red_val[tx * 4 + a][ty] = best[a];
        red_idx[tx * 4 + a][ty] = bidx[a];
    }
    __syncthreads();
    if (t < 64) {
        float bv = red_val[t][0];
        int   bi = red_idx[t][0];
        #pragma unroll
        for (int y = 1; y < 16; ++y) {
            const float v = red_val[t][y];
            const int   i2 = red_idx[t][y];
            if (v < bv || (v == bv && i2 < bi)) { bv = v; bi = i2; }
        }
        idx_i[n0 + t] = bi;
        idx_f[n0 + t] = (float)bi;
    }
}

// ---------------------------------------------------------------------------
// Kernel 3: transpose z [32,256,1024] -> zf [32*1024, 256] (row per point).
// 64x64 LDS tiles, float4 both phases, pad 65 -> max 2-way bank alias (free).
__global__ __launch_bounds__(256) void transpose_kernel(
        const float* __restrict__ z, float* __restrict__ zf) {
    __shared__ float tile[64][65];
    const int bid = blockIdx.x;
    const int b  = bid >> 6;           // 64 tiles per batch image
    const int ct = (bid >> 4) & 3;     // c-tile (4 x 64 = 256)
    const int ht = bid & 15;           // hw-tile (16 x 64 = 1024)
    const int c0 = ct * 64, hw0 = ht * 64;
    const int t = threadIdx.x;
    const int g  = t & 15;             // float4 group within row
    const int r0 = t >> 4;             // 0..15
    const size_t zb = (size_t)b * 262144;

    #pragma unroll
    for (int r = 0; r < 4; ++r) {
        const int c_l = r * 16 + r0;
        const float4 v = *(const float4*)(z + zb + (size_t)(c0 + c_l) * 1024 + hw0 + g * 4);
        tile[c_l][g * 4 + 0] = v.x; tile[c_l][g * 4 + 1] = v.y;
        tile[c_l][g * 4 + 2] = v.z; tile[c_l][g * 4 + 3] = v.w;
    }
    __syncthreads();
    #pragma unroll
    for (int r = 0; r < 4; ++r) {
        const int hw_l = r * 16 + r0;
        float4 v;
        v.x = tile[g * 4 + 0][hw_l]; v.y = tile[g * 4 + 1][hw_l];
        v.z = tile[g * 4 + 2][hw_l]; v.w = tile[g * 4 + 3][hw_l];
        *(float4*)(zf + ((size_t)b * 1024 + hw0 + hw_l) * 256 + c0 + g * 4) = v;
    }
}

// ---------------------------------------------------------------------------
// Kernel 4: histogram of idx + exclusive scan. Single block, 1024 threads.
__global__ void hist_kernel(const int* __restrict__ idx,
                            float* __restrict__ counts,
                            int* __restrict__ hist_out,
                            int* __restrict__ offsets,
                            int* __restrict__ cursor) {
    __shared__ int h[1024];
    __shared__ int scan[1024];
    const int t = threadIdx.x;
    h[t] = 0;
    __syncthreads();
    #pragma unroll
    for (int i = 0; i < 32; ++i) atomicAdd(&h[idx[i * 1024 + t]], 1);
    __syncthreads();
    const int v = h[t];
    counts[t] = (float)v;
    hist_out[t] = v;
    scan[t] = v;
    __syncthreads();
    for (int s = 1; s < 1024; s <<= 1) {
        const int add = (t >= s) ? scan[t - s] : 0;
        __syncthreads();
        scan[t] += add;
        __syncthreads();
    }
    const int excl = scan[t] - v;
    offsets[t] = excl;
    cursor[t] = excl;
}

// ---------------------------------------------------------------------------
// Kernel 5: counting-sort scatter: bucket point ids by code.
__global__ __launch_bounds__(256) void sort_kernel(
        const int* __restrict__ idx, int* __restrict__ cursor,
        int* __restrict__ sorted) {
    const int n = blockIdx.x * 256 + threadIdx.x;
    const int j = idx[n];
    const int pos = atomicAdd(&cursor[j], 1);
    sorted[pos] = n;
}

// ---------------------------------------------------------------------------
// Kernel 6: dw segmented sum + EMA-w. One block per code, thread = channel.
// Zero atomics: register accumulate, coalesced zf rows (1KB per point).
__global__ __launch_bounds__(256) void dw_kernel(
        const float* __restrict__ zf, const int* __restrict__ sorted,
        const int* __restrict__ offsets, const int* __restrict__ hist,
        const float* __restrict__ ema_w, float* __restrict__ new_ema_w_out) {
    const int k = blockIdx.x;
    const int c = threadIdx.x;
    const int start = offsets[k];
    const int cnt = hist[k];
    float acc = 0.0f;
    for (int p = 0; p < cnt; ++p) {
        const int n = sorted[start + p];   // block-uniform -> scalar load
        acc += zf[(size_t)n * Dd + c];
    }
    const float nw = ema_w[(size_t)k * Dd + c] * DECAY + (1.0f - DECAY) * acc;
    new_ema_w_out[(size_t)k * Dd + c] = nw;
}

// ---------------------------------------------------------------------------
// Kernel 7: gather z_q (overwrites zf staging region) + loss partials.
__global__ __launch_bounds__(256) void gather_kernel(
        const float* __restrict__ z, const float* __restrict__ emb,
        const int* __restrict__ idx, float* __restrict__ zq_out,
        float* __restrict__ loss_part) {
    __shared__ float lred[4];
    const int tid = blockIdx.x * 256 + threadIdx.x;
    const int e0 = tid * 4;
    const int c = (e0 >> 10) & 255;
    const int b = e0 >> 18;
    const int n0 = b * 1024 + (e0 & 1023);
    const int4 j4 = *(const int4*)(idx + n0);
    const float4 zv = *(const float4*)(z + e0);
    float4 e;
    e.x = emb[(size_t)j4.x * Dd + c];
    e.y = emb[(size_t)j4.y * Dd + c];
    e.z = emb[(size_t)j4.z * Dd + c];
    e.w = emb[(size_t)j4.w * Dd + c];
    *(float4*)(zq_out + e0) = e;
    const float dx = e.x - zv.x, dy = e.y - zv.y;
    const float dz = e.z - zv.z, dwv = e.w - zv.w;
    float s = dx * dx + dy * dy + dz * dz + dwv * dwv;
    #pragma unroll
    for (int off = 32; off > 0; off >>= 1) s += __shfl_down(s, off);
    if ((threadIdx.x & 63) == 0) lred[threadIdx.x >> 6] = s;
    __syncthreads();
    if (threadIdx.x == 0)
        loss_part[blockIdx.x] = lred[0] + lred[1] + lred[2] + lred[3];
}

// ---------------------------------------------------------------------------
// Kernel 8: cluster-size EMA + Laplace smoothing + loss reduce. 1 block.
__global__ void finalize1_kernel(const float* __restrict__ ema_cs,
                                 const float* __restrict__ counts,
                                 const float* __restrict__ loss_part,
                                 float* __restrict__ cs_out,
                                 float* __restrict__ cs_ws,
                                 float* __restrict__ loss_out) {
    __shared__ float red[1024];
    __shared__ float red2[1024];
    const int k = threadIdx.x;
    const float csr = ema_cs[k] * DECAY + (1.0f - DECAY) * counts[k];
    float lp = 0.0f;
    #pragma unroll
    for (int i = 0; i < 8; ++i) lp += loss_part[i * 1024 + k];
    red[k] = csr;
    red2[k] = lp;
    __syncthreads();
    for (int s = 512; s > 0; s >>= 1) {
        if (k < s) { red[k] += red[k + s]; red2[k] += red2[k + s]; }
        __syncthreads();
    }
    const float nsum = red[0];
    const float cs = (csr + EPSV) / (nsum + (float)Kk * EPSV) * nsum;
    cs_out[k] = cs;
    cs_ws[k] = cs;
    if (k == 0) loss_out[0] = BETA * red2[0] / (float)ZELEM;
}

// ---------------------------------------------------------------------------
// Kernel 9: new_embedding = new_ema_w / cs.
__global__ __launch_bounds__(256) void finalize2_kernel(
        const float* __restrict__ new_ema_w_out, const float* __restrict__ cs_ws,
        float* __restrict__ new_emb_out) {
    const int i = blockIdx.x * 256 + threadIdx.x;
    new_emb_out[i] = new_ema_w_out[i] / cs_ws[i >> 8];
}

// ---------------------------------------------------------------------------
extern "C" void kernel_launch(void* const* d_in, const int* in_sizes, int n_in,
                              void* d_out, int out_size, void* d_ws, size_t ws_size,
                              hipStream_t stream) {
    const float* z      = (const float*)d_in[0];
    const float* emb    = (const float*)d_in[1];
    const float* ema_cs = (const float*)d_in[2];
    const float* ema_w  = (const float*)d_in[3];

    float* out = (float*)d_out;
    float* zq_out        = out;                 // 8388608 (also zf staging)
    float* idx_out_f     = out + 8388608;       // 32768
    float* loss_out      = out + 8421376;       // 1
    float* new_emb_out   = out + 8421377;       // 262144
    float* cs_out        = out + 8683521;       // 1024
    float* new_ema_w_out = out + 8684545;       // 262144

    float* wsf     = (float*)d_ws;
    int*   idx_i   = (int*)d_ws;                // 32768
    int*   sorted  = (int*)d_ws + 32768;        // 32768
    int*   hist    = (int*)d_ws + 65536;        // 1024
    int*   offsets = (int*)d_ws + 66560;        // 1024
    int*   cursor  = (int*)d_ws + 67584;        // 1024
    float* counts  = wsf + 68608;               // 1024
    float* cs_ws   = wsf + 69632;               // 1024
    float* esq     = wsf + 70656;               // 1024
    float* loss_p  = wsf + 71680;               // 8192

    float* zf = zq_out;  // stage transposed z in the zq output region

    esq_kernel<<<Kk, 64, 0, stream>>>(emb, esq);
    dist_argmin_kernel<<<Nn / 64, 256, 0, stream>>>(z, emb, esq, idx_i, idx_out_f);
    transpose_kernel<<<2048, 256, 0, stream>>>(z, zf);
    hist_kernel<<<1, 1024, 0, stream>>>(idx_i, counts, hist, offsets, cursor);
    sort_kernel<<<Nn / 256, 256, 0, stream>>>(idx_i, cursor, sorted);
    dw_kernel<<<Kk, 256, 0, stream>>>(zf, sorted, offsets, hist, ema_w, new_ema_w_out);
    gather_kernel<<<ZELEM / 1024, 256, 0, stream>>>(z, emb, idx_i, zq_out, loss_p);
    finalize1_kernel<<<1, 1024, 0, stream>>>(ema_cs, counts, loss_p, cs_out, cs_ws, loss_out);
    finalize2_kernel<<<Kk * Dd / 256, 256, 0, stream>>>(new_ema_w_out, cs_ws, new_emb_out);
}

// Round 3
// 442.229 us; speedup vs baseline: 4.7266x; 1.7367x over previous
//
#include <hip/hip_runtime.h>

#define DECAY 0.99f
#define BETA 0.25f
#define EPSV 1e-5f

// z: [32, 256, 32, 32] fp32 ; embedding: [1024, 256] ; N = 32*32*32 = 32768
#define Dd 256
#define Kk 1024
#define Nn 32768
#define ZELEM 8388608   // 32*256*32*32

// ---------------------------------------------------------------------------
// Kernel 1: ||e_k||^2 per codebook row. One wave per row.
__global__ void esq_kernel(const float* __restrict__ emb, float* __restrict__ esq) {
    const int k = blockIdx.x;
    const int lane = threadIdx.x;          // 64 lanes
    const float4 v = ((const float4*)(emb + (size_t)k * Dd))[lane];
    float s = v.x * v.x + v.y * v.y + v.z * v.z + v.w * v.w;
    #pragma unroll
    for (int off = 32; off > 0; off >>= 1) s += __shfl_down(s, off);
    if (lane == 0) esq[k] = s;
}

// ---------------------------------------------------------------------------
// Kernel 2: distance + argmin. Block = 256 threads handles 64 points x all K.
__global__ __launch_bounds__(256) void dist_argmin_kernel(
        const float* __restrict__ z, const float* __restrict__ emb,
        const float* __restrict__ esq, int* __restrict__ idx_i,
        float* __restrict__ idx_f) {
    __shared__ float zs[32][64];
    __shared__ float es[32][68];
    __shared__ float red_val[64][16];
    __shared__ int   red_idx[64][16];

    const int t  = threadIdx.x;
    const int tx = t & 15;
    const int ty = t >> 4;
    const int n0 = blockIdx.x * 64;
    const int b   = n0 >> 10;
    const int rem = n0 & 1023;
    const size_t zbase = (size_t)b * (Dd * 1024) + rem;

    float best[4];
    int   bidx[4];
    #pragma unroll
    for (int a = 0; a < 4; ++a) { best[a] = 3.4e38f; bidx[a] = 0; }

    for (int kt = 0; kt < Kk / 64; ++kt) {
        const int k0 = kt * 64;
        float acc[4][4] = {};
        float esql[4];
        #pragma unroll
        for (int q = 0; q < 4; ++q) esql[q] = esq[k0 + ty * 4 + q];

        for (int dc = 0; dc < Dd / 32; ++dc) {
            const int d0 = dc * 32;
            __syncthreads();
            {
                const int i4 = (t & 15) * 4;
                const int dl = t >> 4;
                #pragma unroll
                for (int p = 0; p < 2; ++p) {
                    const int d = dl + p * 16;
                    const float4 v = *(const float4*)(z + zbase + (size_t)(d0 + d) * 1024 + i4);
                    *(float4*)&zs[d][i4] = v;
                }
            }
            {
                const int dl4 = (t & 7) * 4;
                const int kk  = t >> 3;
                #pragma unroll
                for (int p = 0; p < 2; ++p) {
                    const int k = kk + p * 32;
                    const float4 v = *(const float4*)(emb + (size_t)(k0 + k) * Dd + d0 + dl4);
                    es[dl4 + 0][k] = v.x;
                    es[dl4 + 1][k] = v.y;
                    es[dl4 + 2][k] = v.z;
                    es[dl4 + 3][k] = v.w;
                }
            }
            __syncthreads();
            #pragma unroll
            for (int dt = 0; dt < 32; ++dt) {
                const float4 zv = *(const float4*)&zs[dt][tx * 4];
                const float4 ev = *(const float4*)&es[dt][ty * 4];
                const float za[4] = {zv.x, zv.y, zv.z, zv.w};
                const float eb[4] = {ev.x, ev.y, ev.z, ev.w};
                #pragma unroll
                for (int a = 0; a < 4; ++a)
                    #pragma unroll
                    for (int q = 0; q < 4; ++q)
                        acc[a][q] = fmaf(za[a], eb[q], acc[a][q]);
            }
        }
        #pragma unroll
        for (int a = 0; a < 4; ++a) {
            #pragma unroll
            for (int q = 0; q < 4; ++q) {
                const float val = esql[q] - 2.0f * acc[a][q];
                const int ki = k0 + ty * 4 + q;
                if (val < best[a] || (val == best[a] && ki < bidx[a])) {
                    best[a] = val; bidx[a] = ki;
                }
            }
        }
    }

    __syncthreads();
    #pragma unroll
    for (int a = 0; a < 4; ++a) {
        red_val[tx * 4 + a][ty] = best[a];
        red_idx[tx * 4 + a][ty] = bidx[a];
    }
    __syncthreads();
    if (t < 64) {
        float bv = red_val[t][0];
        int   bi = red_idx[t][0];
        #pragma unroll
        for (int y = 1; y < 16; ++y) {
            const float v = red_val[t][y];
            const int   i2 = red_idx[t][y];
            if (v < bv || (v == bv && i2 < bi)) { bv = v; bi = i2; }
        }
        idx_i[n0 + t] = bi;
        idx_f[n0 + t] = (float)bi;
    }
}

// ---------------------------------------------------------------------------
// Kernel 3: transpose z [32,256,1024] -> zf [32*1024, 256] (row per point).
__global__ __launch_bounds__(256) void transpose_kernel(
        const float* __restrict__ z, float* __restrict__ zf) {
    __shared__ float tile[64][65];
    const int bid = blockIdx.x;
    const int b  = bid >> 6;
    const int ct = (bid >> 4) & 3;
    const int ht = bid & 15;
    const int c0 = ct * 64, hw0 = ht * 64;
    const int t = threadIdx.x;
    const int g  = t & 15;
    const int r0 = t >> 4;
    const size_t zb = (size_t)b * 262144;

    #pragma unroll
    for (int r = 0; r < 4; ++r) {
        const int c_l = r * 16 + r0;
        const float4 v = *(const float4*)(z + zb + (size_t)(c0 + c_l) * 1024 + hw0 + g * 4);
        tile[c_l][g * 4 + 0] = v.x; tile[c_l][g * 4 + 1] = v.y;
        tile[c_l][g * 4 + 2] = v.z; tile[c_l][g * 4 + 3] = v.w;
    }
    __syncthreads();
    #pragma unroll
    for (int r = 0; r < 4; ++r) {
        const int hw_l = r * 16 + r0;
        float4 v;
        v.x = tile[g * 4 + 0][hw_l]; v.y = tile[g * 4 + 1][hw_l];
        v.z = tile[g * 4 + 2][hw_l]; v.w = tile[g * 4 + 3][hw_l];
        *(float4*)(zf + ((size_t)b * 1024 + hw0 + hw_l) * 256 + c0 + g * 4) = v;
    }
}

// ---------------------------------------------------------------------------
// Kernel 4: histogram of idx + exclusive scan. Single block, 1024 threads.
__global__ void hist_kernel(const int* __restrict__ idx,
                            float* __restrict__ counts,
                            int* __restrict__ offsets,
                            int* __restrict__ cursor) {
    __shared__ int h[1024];
    __shared__ int scan[1024];
    const int t = threadIdx.x;
    h[t] = 0;
    __syncthreads();
    #pragma unroll
    for (int i = 0; i < 32; ++i) atomicAdd(&h[idx[i * 1024 + t]], 1);
    __syncthreads();
    const int v = h[t];
    counts[t] = (float)v;
    scan[t] = v;
    __syncthreads();
    for (int s = 1; s < 1024; s <<= 1) {
        const int add = (t >= s) ? scan[t - s] : 0;
        __syncthreads();
        scan[t] += add;
        __syncthreads();
    }
    const int excl = scan[t] - v;
    offsets[t] = excl;
    cursor[t] = excl;
}

// ---------------------------------------------------------------------------
// Kernel 5: counting-sort scatter: bucket point ids by code; also record
// the code id at each sorted position (for the segmented reduction).
__global__ __launch_bounds__(256) void sort_kernel(
        const int* __restrict__ idx, int* __restrict__ cursor,
        int* __restrict__ sorted, int* __restrict__ codes_sorted) {
    const int n = blockIdx.x * 256 + threadIdx.x;
    const int j = idx[n];
    const int pos = atomicAdd(&cursor[j], 1);
    sorted[pos] = n;
    codes_sorted[pos] = j;
}

// ---------------------------------------------------------------------------
// Kernel 6: balanced segmented reduction over sorted points.
// 512 blocks x 64-point tiles; thread = channel; register accumulate;
// one atomicAdd per segment boundary (block-uniform branch).
__global__ __launch_bounds__(256) void dw_seg_kernel(
        const float* __restrict__ zf, const int* __restrict__ sorted,
        const int* __restrict__ codes_sorted, float* __restrict__ dw) {
    __shared__ int sid[64];
    __shared__ int scode[65];
    const int t = threadIdx.x;
    const int p0 = blockIdx.x * 64;
    if (t < 64) {
        sid[t] = sorted[p0 + t];
        scode[t] = codes_sorted[p0 + t];
    }
    if (t == 64) scode[64] = -1;   // always flush at tile end
    __syncthreads();
    const int c = t;
    float acc = 0.0f;
    #pragma unroll 8
    for (int p = 0; p < 64; ++p) {
        acc += zf[(size_t)sid[p] * Dd + c];
        if (scode[p] != scode[p + 1]) {          // block-uniform
            atomicAdd(&dw[(size_t)scode[p] * Dd + c], acc);
            acc = 0.0f;
        }
    }
}

// ---------------------------------------------------------------------------
// Kernel 7: gather z_q (overwrites zf staging region) + loss partials.
__global__ __launch_bounds__(256) void gather_kernel(
        const float* __restrict__ z, const float* __restrict__ emb,
        const int* __restrict__ idx, float* __restrict__ zq_out,
        float* __restrict__ loss_part) {
    __shared__ float lred[4];
    const int tid = blockIdx.x * 256 + threadIdx.x;
    const int e0 = tid * 4;
    const int c = (e0 >> 10) & 255;
    const int b = e0 >> 18;
    const int n0 = b * 1024 + (e0 & 1023);
    const int4 j4 = *(const int4*)(idx + n0);
    const float4 zv = *(const float4*)(z + e0);
    float4 e;
    e.x = emb[(size_t)j4.x * Dd + c];
    e.y = emb[(size_t)j4.y * Dd + c];
    e.z = emb[(size_t)j4.z * Dd + c];
    e.w = emb[(size_t)j4.w * Dd + c];
    *(float4*)(zq_out + e0) = e;
    const float dx = e.x - zv.x, dy = e.y - zv.y;
    const float dz = e.z - zv.z, dwv = e.w - zv.w;
    float s = dx * dx + dy * dy + dz * dz + dwv * dwv;
    #pragma unroll
    for (int off = 32; off > 0; off >>= 1) s += __shfl_down(s, off);
    if ((threadIdx.x & 63) == 0) lred[threadIdx.x >> 6] = s;
    __syncthreads();
    if (threadIdx.x == 0)
        loss_part[blockIdx.x] = lred[0] + lred[1] + lred[2] + lred[3];
}

// ---------------------------------------------------------------------------
// Kernel 8: cluster-size EMA + Laplace smoothing + loss reduce. 1 block.
__global__ void finalize1_kernel(const float* __restrict__ ema_cs,
                                 const float* __restrict__ counts,
                                 const float* __restrict__ loss_part,
                                 float* __restrict__ cs_out,
                                 float* __restrict__ cs_ws,
                                 float* __restrict__ loss_out) {
    __shared__ float red[1024];
    __shared__ float red2[1024];
    const int k = threadIdx.x;
    const float csr = ema_cs[k] * DECAY + (1.0f - DECAY) * counts[k];
    float lp = 0.0f;
    #pragma unroll
    for (int i = 0; i < 8; ++i) lp += loss_part[i * 1024 + k];
    red[k] = csr;
    red2[k] = lp;
    __syncthreads();
    for (int s = 512; s > 0; s >>= 1) {
        if (k < s) { red[k] += red[k + s]; red2[k] += red2[k + s]; }
        __syncthreads();
    }
    const float nsum = red[0];
    const float cs = (csr + EPSV) / (nsum + (float)Kk * EPSV) * nsum;
    cs_out[k] = cs;
    cs_ws[k] = cs;
    if (k == 0) loss_out[0] = BETA * red2[0] / (float)ZELEM;
}

// ---------------------------------------------------------------------------
// Kernel 9: new_ema_w = EMA(ema_w, dw); new_emb = new_ema_w / cs.
// NOTE: dw aliases new_emb_out — each thread reads dw[i] then overwrites
// new_emb_out[i] (same index), so the aliasing is safe.
__global__ __launch_bounds__(256) void finalize2_kernel(
        const float* __restrict__ ema_w, const float* __restrict__ dw,
        const float* __restrict__ cs_ws,
        float* __restrict__ new_emb_out, float* __restrict__ new_ema_w_out) {
    const int i = blockIdx.x * 256 + threadIdx.x;
    const float nw = ema_w[i] * DECAY + (1.0f - DECAY) * dw[i];
    const float cs = cs_ws[i >> 8];
    new_ema_w_out[i] = nw;
    new_emb_out[i]   = nw / cs;
}

// ---------------------------------------------------------------------------
extern "C" void kernel_launch(void* const* d_in, const int* in_sizes, int n_in,
                              void* d_out, int out_size, void* d_ws, size_t ws_size,
                              hipStream_t stream) {
    const float* z      = (const float*)d_in[0];
    const float* emb    = (const float*)d_in[1];
    const float* ema_cs = (const float*)d_in[2];
    const float* ema_w  = (const float*)d_in[3];

    float* out = (float*)d_out;
    float* zq_out        = out;                 // 8388608 (also zf staging)
    float* idx_out_f     = out + 8388608;       // 32768
    float* loss_out      = out + 8421376;       // 1
    float* new_emb_out   = out + 8421377;       // 262144 (also dw staging)
    float* cs_out        = out + 8683521;       // 1024
    float* new_ema_w_out = out + 8684545;       // 262144

    float* wsf      = (float*)d_ws;
    int*   idx_i    = (int*)d_ws;               // 32768
    int*   sorted   = (int*)d_ws + 32768;       // 32768
    int*   codes_s  = (int*)d_ws + 65536;       // 32768
    int*   offsets  = (int*)d_ws + 98304;       // 1024
    int*   cursor   = (int*)d_ws + 99328;       // 1024
    float* counts   = wsf + 100352;             // 1024
    float* cs_ws    = wsf + 101376;             // 1024
    float* esq      = wsf + 102400;             // 1024
    float* loss_p   = wsf + 103424;             // 8192

    float* zf = zq_out;        // transposed z staged in zq output region
    float* dw = new_emb_out;   // dw staged in new_embedding output region

    hipMemsetAsync(dw, 0, (size_t)Kk * Dd * sizeof(float), stream);

    esq_kernel<<<Kk, 64, 0, stream>>>(emb, esq);
    dist_argmin_kernel<<<Nn / 64, 256, 0, stream>>>(z, emb, esq, idx_i, idx_out_f);
    transpose_kernel<<<2048, 256, 0, stream>>>(z, zf);
    hist_kernel<<<1, 1024, 0, stream>>>(idx_i, counts, offsets, cursor);
    sort_kernel<<<Nn / 256, 256, 0, stream>>>(idx_i, cursor, sorted, codes_s);
    dw_seg_kernel<<<Nn / 64, 256, 0, stream>>>(zf, sorted, codes_s, dw);
    gather_kernel<<<ZELEM / 1024, 256, 0, stream>>>(z, emb, idx_i, zq_out, loss_p);
    finalize1_kernel<<<1, 1024, 0, stream>>>(ema_cs, counts, loss_p, cs_out, cs_ws, loss_out);
    finalize2_kernel<<<Kk * Dd / 256, 256, 0, stream>>>(ema_w, dw, cs_ws, new_emb_out, new_ema_w_out);
}

// Round 4
// 392.787 us; speedup vs baseline: 5.3216x; 1.1259x over previous
//
#include <hip/hip_runtime.h>

typedef unsigned long long ull;
typedef __attribute__((ext_vector_type(8))) short bf16x8;
typedef __attribute__((ext_vector_type(4))) float f32x4;
typedef __attribute__((ext_vector_type(8))) unsigned short u16x8;

#define DECAY 0.99f
#define BETA 0.25f
#define EPSV 1e-5f
#define EPSGAP 0.05f

// z: [32, 256, 32, 32] fp32 ; embedding: [1024, 256] ; N = 32*32*32 = 32768
#define Dd 256
#define Kk 1024
#define Nn 32768
#define ZELEM 8388608

__device__ __forceinline__ unsigned short f2bf(float f) {
    unsigned int x = __float_as_uint(f);
    x += 0x7FFFu + ((x >> 16) & 1u);          // RNE
    return (unsigned short)(x >> 16);
}
__device__ __forceinline__ float bf2f(unsigned short b) {
    return __uint_as_float(((unsigned int)b) << 16);
}
__device__ __forceinline__ unsigned mono(unsigned b) {
    return b ^ (((int)b >> 31) | 0x80000000u);   // monotone float->uint
}
__device__ __forceinline__ float unmono(unsigned m) {
    unsigned b = (m & 0x80000000u) ? (m ^ 0x80000000u) : ~m;
    return __uint_as_float(b);
}

// ---------------------------------------------------------------------------
// Kernel 1: ||e_k||^2 per codebook row (fp32 exact). One wave per row.
__global__ void esq_kernel(const float* __restrict__ emb, float* __restrict__ esq) {
    const int k = blockIdx.x;
    const int lane = threadIdx.x;
    const float4 v = ((const float4*)(emb + (size_t)k * Dd))[lane];
    float s = v.x * v.x + v.y * v.y + v.z * v.z + v.w * v.w;
    #pragma unroll
    for (int off = 32; off > 0; off >>= 1) s += __shfl_down(s, off);
    if (lane == 0) esq[k] = s;
}

// ---------------------------------------------------------------------------
// Kernel 2: MFMA distance + top-2 argmin. Grid 2048 = 256 m-tiles x 8 n-tiles.
// bid = nt*256 + mt so all 8 n-tiles of one z-tile share bid%8 (same XCD -> L2 reuse).
// 3-pass bf16 split GEMM: dot = zh*eh + zh*el + zl*eh (fp32 accumulate).
__global__ __launch_bounds__(256) void dist_mfma_kernel(
        const float* __restrict__ z, const float* __restrict__ emb,
        const float* __restrict__ esq,
        ull* __restrict__ P1, ull* __restrict__ P2) {
    // row stride 40 shorts = 80B: 16B-aligned rows, odd bank walk (17 lines)
    __shared__ unsigned short zh[128][40], zl[128][40], eh[128][40], el[128][40];

    const int bid = blockIdx.x;
    const int mt = bid & 255, nt = bid >> 8;
    const int t = threadIdx.x;
    const int w = t >> 6, L = t & 63;
    const int quad = L >> 4, lr = L & 15;
    const int wm = (w & 1) * 64, wn = (w >> 1) * 64;
    const size_t zbase = (size_t)(mt >> 3) * 262144 + (size_t)(mt & 7) * 128;
    const int n0 = nt * 128;

    f32x4 acc[4][4];
    #pragma unroll
    for (int mi = 0; mi < 4; ++mi)
        #pragma unroll
        for (int ni = 0; ni < 4; ++ni) acc[mi][ni] = (f32x4){0.f, 0.f, 0.f, 0.f};

    const int m_ = t & 127, half = t >> 7;   // z staging role
    const int ne = t >> 1, kq = t & 1;       // e staging role

    for (int ch = 0; ch < 8; ++ch) {
        const int c0 = ch * 32;
        __syncthreads();
        // ---- stage z tile [128 m][32 k] as hi/lo bf16 (transposed from [k][m])
        #pragma unroll
        for (int kg = 0; kg < 2; ++kg) {
            const int kk = half * 16 + kg * 8;
            float v[8];
            #pragma unroll
            for (int i = 0; i < 8; ++i)
                v[i] = z[zbase + (size_t)(c0 + kk + i) * 1024 + m_];
            u16x8 hi, lo;
            #pragma unroll
            for (int i = 0; i < 8; ++i) {
                const unsigned short h = f2bf(v[i]);
                hi[i] = h;
                lo[i] = f2bf(v[i] - bf2f(h));
            }
            *(u16x8*)&zh[m_][kk] = hi;
            *(u16x8*)&zl[m_][kk] = lo;
        }
        // ---- stage e tile [128 n][32 k] (row-major already)
        {
            float v[16];
            #pragma unroll
            for (int j = 0; j < 4; ++j) {
                const float4 e4 = *(const float4*)(emb + (size_t)(n0 + ne) * Dd + c0 + kq * 16 + j * 4);
                v[j * 4 + 0] = e4.x; v[j * 4 + 1] = e4.y;
                v[j * 4 + 2] = e4.z; v[j * 4 + 3] = e4.w;
            }
            u16x8 hi0, lo0, hi1, lo1;
            #pragma unroll
            for (int i = 0; i < 8; ++i) {
                unsigned short h = f2bf(v[i]);
                hi0[i] = h; lo0[i] = f2bf(v[i] - bf2f(h));
                h = f2bf(v[8 + i]);
                hi1[i] = h; lo1[i] = f2bf(v[8 + i] - bf2f(h));
            }
            *(u16x8*)&eh[ne][kq * 16]     = hi0;
            *(u16x8*)&eh[ne][kq * 16 + 8] = hi1;
            *(u16x8*)&el[ne][kq * 16]     = lo0;
            *(u16x8*)&el[ne][kq * 16 + 8] = lo1;
        }
        __syncthreads();
        // ---- fragments + MFMA (A: m=lane&15,k=quad*8+j ; B mirrored ; C: col=lane&15,row=quad*4+reg)
        bf16x8 ah[4], al[4], bh[4], bl[4];
        #pragma unroll
        for (int mi = 0; mi < 4; ++mi) {
            ah[mi] = *(const bf16x8*)&zh[wm + mi * 16 + lr][quad * 8];
            al[mi] = *(const bf16x8*)&zl[wm + mi * 16 + lr][quad * 8];
        }
        #pragma unroll
        for (int ni = 0; ni < 4; ++ni) {
            bh[ni] = *(const bf16x8*)&eh[wn + ni * 16 + lr][quad * 8];
            bl[ni] = *(const bf16x8*)&el[wn + ni * 16 + lr][quad * 8];
        }
        #pragma unroll
        for (int mi = 0; mi < 4; ++mi)
            #pragma unroll
            for (int ni = 0; ni < 4; ++ni) {
                acc[mi][ni] = __builtin_amdgcn_mfma_f32_16x16x32_bf16(ah[mi], bh[ni], acc[mi][ni], 0, 0, 0);
                acc[mi][ni] = __builtin_amdgcn_mfma_f32_16x16x32_bf16(ah[mi], bl[ni], acc[mi][ni], 0, 0, 0);
                acc[mi][ni] = __builtin_amdgcn_mfma_f32_16x16x32_bf16(al[mi], bh[ni], acc[mi][ni], 0, 0, 0);
            }
    }

    // ---- epilogue: per-row top-2 within this block's 128 codes, then global
    // lock-free top-2 merge: old=atomicMin(P1,best); atomicMin(P2,min(max(old,best),second))
    float esql[4];
    #pragma unroll
    for (int ni = 0; ni < 4; ++ni) esql[ni] = esq[n0 + wn + ni * 16 + lr];

    #pragma unroll
    for (int mi = 0; mi < 4; ++mi) {
        #pragma unroll
        for (int reg = 0; reg < 4; ++reg) {
            ull b = ~0ull, s = ~0ull;
            #pragma unroll
            for (int ni = 0; ni < 4; ++ni) {
                const float val = esql[ni] - 2.0f * acc[mi][ni][reg];
                const unsigned kg = (unsigned)(n0 + wn + ni * 16 + lr);
                const ull pk = ((ull)mono(__float_as_uint(val)) << 32) | kg;
                if (pk < b) { s = b; b = pk; }
                else if (pk < s) { s = pk; }
            }
            #pragma unroll
            for (int d = 1; d < 16; d <<= 1) {
                const ull ob = __shfl_xor(b, d);
                const ull os = __shfl_xor(s, d);
                const ull nb = ob < b ? ob : b;
                const ull mx = ob < b ? b : ob;
                ull ns = os < s ? os : s;
                ns = mx < ns ? mx : ns;
                b = nb; s = ns;
            }
            if (lr == 0) {
                const int row = mt * 128 + wm + mi * 16 + quad * 4 + reg;
                const ull old = atomicMin(&P1[row], b);
                const ull lo2 = old > b ? old : b;
                const ull sub = lo2 < s ? lo2 : s;
                atomicMin(&P2[row], sub);
            }
        }
    }
}

// ---------------------------------------------------------------------------
// Kernel 3: unpack argmin; flag rows with top-2 gap < EPSGAP for exact fixup.
__global__ __launch_bounds__(256) void extract_kernel(
        const ull* __restrict__ P1, const ull* __restrict__ P2,
        int* __restrict__ idx_i, float* __restrict__ idx_f,
        int* __restrict__ flagcnt, int* __restrict__ flaglist) {
    const int n = blockIdx.x * 256 + threadIdx.x;
    const ull p1 = P1[n], p2 = P2[n];
    const int k = (int)(unsigned)(p1 & 0xFFFFFFFFull);
    idx_i[n] = k;
    idx_f[n] = (float)k;
    const float v1 = unmono((unsigned)(p1 >> 32));
    const float v2 = unmono((unsigned)(p2 >> 32));
    if (v2 - v1 < EPSGAP) {
        const int pos = atomicAdd(flagcnt, 1);
        flaglist[pos] = n;
    }
}

// ---------------------------------------------------------------------------
// Kernel 4: exact fp32 re-argmin for flagged points. One point per block.
__global__ __launch_bounds__(256) void fixup_kernel(
        const float* __restrict__ z, const float* __restrict__ emb,
        const float* __restrict__ esq, const int* __restrict__ flagcnt,
        const int* __restrict__ flaglist,
        int* __restrict__ idx_i, float* __restrict__ idx_f) {
    __shared__ float zrow[256];
    __shared__ ull red[256];
    const int t = threadIdx.x;
    const int total = flagcnt[0];
    for (int fi = blockIdx.x; fi < total; fi += 64) {
        const int n = flaglist[fi];
        const int b = n >> 10, hw = n & 1023;
        __syncthreads();
        zrow[t] = z[(size_t)b * 262144 + (size_t)t * 1024 + hw];
        __syncthreads();
        ull best = ~0ull;
        #pragma unroll
        for (int kc = 0; kc < 4; ++kc) {
            const int k = t * 4 + kc;
            const float* ep = emb + (size_t)k * Dd;
            float dot = 0.0f;
            #pragma unroll 8
            for (int c4 = 0; c4 < 64; ++c4) {
                const float4 e4 = *(const float4*)(ep + c4 * 4);
                const float4 z4 = *(const float4*)&zrow[c4 * 4];
                dot = fmaf(z4.x, e4.x, dot);
                dot = fmaf(z4.y, e4.y, dot);
                dot = fmaf(z4.z, e4.z, dot);
                dot = fmaf(z4.w, e4.w, dot);
            }
            const float val = esq[k] - 2.0f * dot;
            const ull pk = ((ull)mono(__float_as_uint(val)) << 32) | (unsigned)k;
            if (pk < best) best = pk;
        }
        red[t] = best;
        __syncthreads();
        for (int s = 128; s > 0; s >>= 1) {
            if (t < s) { if (red[t + s] < red[t]) red[t] = red[t + s]; }
            __syncthreads();
        }
        if (t == 0) {
            const int k = (int)(unsigned)(red[0] & 0xFFFFFFFFull);
            idx_i[n] = k;
            idx_f[n] = (float)k;
        }
    }
}

// ---------------------------------------------------------------------------
// Kernel 5: transpose z [32,256,1024] -> zf [32768, 256].
__global__ __launch_bounds__(256) void transpose_kernel(
        const float* __restrict__ z, float* __restrict__ zf) {
    __shared__ float tile[64][65];
    const int bid = blockIdx.x;
    const int b  = bid >> 6;
    const int ct = (bid >> 4) & 3;
    const int ht = bid & 15;
    const int c0 = ct * 64, hw0 = ht * 64;
    const int t = threadIdx.x;
    const int g  = t & 15;
    const int r0 = t >> 4;
    const size_t zb = (size_t)b * 262144;

    #pragma unroll
    for (int r = 0; r < 4; ++r) {
        const int c_l = r * 16 + r0;
        const float4 v = *(const float4*)(z + zb + (size_t)(c0 + c_l) * 1024 + hw0 + g * 4);
        tile[c_l][g * 4 + 0] = v.x; tile[c_l][g * 4 + 1] = v.y;
        tile[c_l][g * 4 + 2] = v.z; tile[c_l][g * 4 + 3] = v.w;
    }
    __syncthreads();
    #pragma unroll
    for (int r = 0; r < 4; ++r) {
        const int hw_l = r * 16 + r0;
        float4 v;
        v.x = tile[g * 4 + 0][hw_l]; v.y = tile[g * 4 + 1][hw_l];
        v.z = tile[g * 4 + 2][hw_l]; v.w = tile[g * 4 + 3][hw_l];
        *(float4*)(zf + ((size_t)b * 1024 + hw0 + hw_l) * 256 + c0 + g * 4) = v;
    }
}

// ---------------------------------------------------------------------------
// Kernel 6: histogram of idx + exclusive scan. Single block, 1024 threads.
__global__ void hist_kernel(const int* __restrict__ idx,
                            float* __restrict__ counts,
                            int* __restrict__ offsets,
                            int* __restrict__ cursor) {
    __shared__ int h[1024];
    __shared__ int scan[1024];
    const int t = threadIdx.x;
    h[t] = 0;
    __syncthreads();
    #pragma unroll
    for (int i = 0; i < 32; ++i) atomicAdd(&h[idx[i * 1024 + t]], 1);
    __syncthreads();
    const int v = h[t];
    counts[t] = (float)v;
    scan[t] = v;
    __syncthreads();
    for (int s = 1; s < 1024; s <<= 1) {
        const int add = (t >= s) ? scan[t - s] : 0;
        __syncthreads();
        scan[t] += add;
        __syncthreads();
    }
    const int excl = scan[t] - v;
    offsets[t] = excl;
    cursor[t] = excl;
}

// ---------------------------------------------------------------------------
// Kernel 7: counting-sort scatter.
__global__ __launch_bounds__(256) void sort_kernel(
        const int* __restrict__ idx, int* __restrict__ cursor,
        int* __restrict__ sorted, int* __restrict__ codes_sorted) {
    const int n = blockIdx.x * 256 + threadIdx.x;
    const int j = idx[n];
    const int pos = atomicAdd(&cursor[j], 1);
    sorted[pos] = n;
    codes_sorted[pos] = j;
}

// ---------------------------------------------------------------------------
// Kernel 8: balanced segmented reduction -> dw (atomic per segment boundary).
__global__ __launch_bounds__(256) void dw_seg_kernel(
        const float* __restrict__ zf, const int* __restrict__ sorted,
        const int* __restrict__ codes_sorted, float* __restrict__ dw) {
    __shared__ int sid[64];
    __shared__ int scode[65];
    const int t = threadIdx.x;
    const int p0 = blockIdx.x * 64;
    if (t < 64) {
        sid[t] = sorted[p0 + t];
        scode[t] = codes_sorted[p0 + t];
    }
    if (t == 64) scode[64] = -1;
    __syncthreads();
    const int c = t;
    float acc = 0.0f;
    #pragma unroll 8
    for (int p = 0; p < 64; ++p) {
        acc += zf[(size_t)sid[p] * Dd + c];
        if (scode[p] != scode[p + 1]) {
            atomicAdd(&dw[(size_t)scode[p] * Dd + c], acc);
            acc = 0.0f;
        }
    }
}

// ---------------------------------------------------------------------------
// Kernel 9: gather z_q (overwrites zf staging region) + loss partials.
__global__ __launch_bounds__(256) void gather_kernel(
        const float* __restrict__ z, const float* __restrict__ emb,
        const int* __restrict__ idx, float* __restrict__ zq_out,
        float* __restrict__ loss_part) {
    __shared__ float lred[4];
    const int tid = blockIdx.x * 256 + threadIdx.x;
    const int e0 = tid * 4;
    const int c = (e0 >> 10) & 255;
    const int b = e0 >> 18;
    const int n0 = b * 1024 + (e0 & 1023);
    const int4 j4 = *(const int4*)(idx + n0);
    const float4 zv = *(const float4*)(z + e0);
    float4 e;
    e.x = emb[(size_t)j4.x * Dd + c];
    e.y = emb[(size_t)j4.y * Dd + c];
    e.z = emb[(size_t)j4.z * Dd + c];
    e.w = emb[(size_t)j4.w * Dd + c];
    *(float4*)(zq_out + e0) = e;
    const float dx = e.x - zv.x, dy = e.y - zv.y;
    const float dz = e.z - zv.z, dwv = e.w - zv.w;
    float s = dx * dx + dy * dy + dz * dz + dwv * dwv;
    #pragma unroll
    for (int off = 32; off > 0; off >>= 1) s += __shfl_down(s, off);
    if ((threadIdx.x & 63) == 0) lred[threadIdx.x >> 6] = s;
    __syncthreads();
    if (threadIdx.x == 0)
        loss_part[blockIdx.x] = lred[0] + lred[1] + lred[2] + lred[3];
}

// ---------------------------------------------------------------------------
// Kernel 10: cluster-size EMA + Laplace smoothing + loss reduce. 1 block.
__global__ void finalize1_kernel(const float* __restrict__ ema_cs,
                                 const float* __restrict__ counts,
                                 const float* __restrict__ loss_part,
                                 float* __restrict__ cs_out,
                                 float* __restrict__ cs_ws,
                                 float* __restrict__ loss_out) {
    __shared__ float red[1024];
    __shared__ float red2[1024];
    const int k = threadIdx.x;
    const float csr = ema_cs[k] * DECAY + (1.0f - DECAY) * counts[k];
    float lp = 0.0f;
    #pragma unroll
    for (int i = 0; i < 8; ++i) lp += loss_part[i * 1024 + k];
    red[k] = csr;
    red2[k] = lp;
    __syncthreads();
    for (int s = 512; s > 0; s >>= 1) {
        if (k < s) { red[k] += red[k + s]; red2[k] += red2[k + s]; }
        __syncthreads();
    }
    const float nsum = red[0];
    const float cs = (csr + EPSV) / (nsum + (float)Kk * EPSV) * nsum;
    cs_out[k] = cs;
    cs_ws[k] = cs;
    if (k == 0) loss_out[0] = BETA * red2[0] / (float)ZELEM;
}

// ---------------------------------------------------------------------------
// Kernel 11: new_ema_w = EMA(ema_w, dw); new_emb = new_ema_w / cs.
// dw aliases new_emb_out; each thread reads dw[i] then overwrites same i.
__global__ __launch_bounds__(256) void finalize2_kernel(
        const float* __restrict__ ema_w, const float* __restrict__ dw,
        const float* __restrict__ cs_ws,
        float* __restrict__ new_emb_out, float* __restrict__ new_ema_w_out) {
    const int i = blockIdx.x * 256 + threadIdx.x;
    const float nw = ema_w[i] * DECAY + (1.0f - DECAY) * dw[i];
    const float cs = cs_ws[i >> 8];
    new_ema_w_out[i] = nw;
    new_emb_out[i]   = nw / cs;
}

// ---------------------------------------------------------------------------
extern "C" void kernel_launch(void* const* d_in, const int* in_sizes, int n_in,
                              void* d_out, int out_size, void* d_ws, size_t ws_size,
                              hipStream_t stream) {
    const float* z      = (const float*)d_in[0];
    const float* emb    = (const float*)d_in[1];
    const float* ema_cs = (const float*)d_in[2];
    const float* ema_w  = (const float*)d_in[3];

    float* out = (float*)d_out;
    float* zq_out        = out;                 // 8388608 (also zf staging)
    float* idx_out_f     = out + 8388608;       // 32768
    float* loss_out      = out + 8421376;       // 1
    float* new_emb_out   = out + 8421377;       // 262144 (also dw staging)
    float* cs_out        = out + 8683521;       // 1024
    float* new_ema_w_out = out + 8684545;       // 262144

    int*   idx_i    = (int*)d_ws;               // 32768
    int*   sorted   = idx_i + 32768;            // 32768
    int*   codes_s  = sorted + 32768;           // 32768
    int*   offsets  = codes_s + 32768;          // 1024
    int*   cursor   = offsets + 1024;           // 1024
    float* counts   = (float*)(cursor + 1024);  // 1024
    float* cs_ws    = counts + 1024;            // 1024
    float* esq      = cs_ws + 1024;             // 1024
    float* loss_p   = esq + 1024;               // 8192
    ull*   P1       = (ull*)(loss_p + 8192);    // 32768 u64 (8B-aligned offset)
    ull*   P2       = P1 + 32768;               // 32768 u64
    int*   flagcnt  = (int*)(P2 + 32768);       // 1
    int*   flaglist = flagcnt + 1;              // 32768

    float* zf = zq_out;        // transposed z staged in zq output region
    float* dw = new_emb_out;   // dw staged in new_embedding output region

    hipMemsetAsync(dw, 0, (size_t)Kk * Dd * sizeof(float), stream);
    hipMemsetAsync(P1, 0xFF, (size_t)Nn * 2 * sizeof(ull), stream);
    hipMemsetAsync(flagcnt, 0, sizeof(int), stream);

    esq_kernel<<<Kk, 64, 0, stream>>>(emb, esq);
    dist_mfma_kernel<<<2048, 256, 0, stream>>>(z, emb, esq, P1, P2);
    extract_kernel<<<Nn / 256, 256, 0, stream>>>(P1, P2, idx_i, idx_out_f, flagcnt, flaglist);
    fixup_kernel<<<64, 256, 0, stream>>>(z, emb, esq, flagcnt, flaglist, idx_i, idx_out_f);
    transpose_kernel<<<2048, 256, 0, stream>>>(z, zf);
    hist_kernel<<<1, 1024, 0, stream>>>(idx_i, counts, offsets, cursor);
    sort_kernel<<<Nn / 256, 256, 0, stream>>>(idx_i, cursor, sorted, codes_s);
    dw_seg_kernel<<<Nn / 64, 256, 0, stream>>>(zf, sorted, codes_s, dw);
    gather_kernel<<<ZELEM / 1024, 256, 0, stream>>>(z, emb, idx_i, zq_out, loss_p);
    finalize1_kernel<<<1, 1024, 0, stream>>>(ema_cs, counts, loss_p, cs_out, cs_ws, loss_out);
    finalize2_kernel<<<Kk * Dd / 256, 256, 0, stream>>>(ema_w, dw, cs_ws, new_emb_out, new_ema_w_out);
}

// Round 5
// 368.255 us; speedup vs baseline: 5.6761x; 1.0666x over previous
//
#include <hip/hip_runtime.h>

typedef unsigned long long ull;
typedef __attribute__((ext_vector_type(8))) short bf16x8;
typedef __attribute__((ext_vector_type(4))) float f32x4;
typedef __attribute__((ext_vector_type(8))) unsigned short u16x8;

#define DECAY 0.99f
#define BETA 0.25f
#define EPSV 1e-5f
#define EPSGAP 0.05f

// z: [32, 256, 32, 32] fp32 ; embedding: [1024, 256] ; N = 32*32*32 = 32768
#define Dd 256
#define Kk 1024
#define Nn 32768
#define ZELEM 8388608

__device__ __forceinline__ unsigned short f2bf(float f) {
    unsigned int x = __float_as_uint(f);
    x += 0x7FFFu + ((x >> 16) & 1u);          // RNE
    return (unsigned short)(x >> 16);
}
__device__ __forceinline__ float bf2f(unsigned short b) {
    return __uint_as_float(((unsigned int)b) << 16);
}
__device__ __forceinline__ unsigned mono(unsigned b) {
    return b ^ (((int)b >> 31) | 0x80000000u);   // monotone float->uint
}
__device__ __forceinline__ float unmono(unsigned m) {
    unsigned b = (m & 0x80000000u) ? (m ^ 0x80000000u) : ~m;
    return __uint_as_float(b);
}

// ---------------------------------------------------------------------------
// Kernel 1: pre-split embedding into MFMA-B-fragment order (hi/lo bf16),
// compute esq, and zero hist_g / flagcnt. 64 blocks (one per 16-code nsub).
// Fragment layout: idx = ((nsub*8 + kc)*64 + lane)*8 + j
//   lane = quad*16 + (n&15), quad = (k_local>>3), j = k_local&7, k = kc*32+k_local
__global__ __launch_bounds__(256) void prep_e_kernel(
        const float* __restrict__ emb, unsigned short* __restrict__ ehg,
        unsigned short* __restrict__ elg, float* __restrict__ esq,
        int* __restrict__ hist_g, int* __restrict__ flagcnt) {
    const int nsub = blockIdx.x;
    const int t = threadIdx.x;
    // zero hist_g (16 entries per block) + flagcnt
    if (t < 16) hist_g[nsub * 16 + t] = 0;
    if (nsub == 0 && t == 16) flagcnt[0] = 0;

    #pragma unroll
    for (int it = 0; it < 2; ++it) {
        const int item = it * 256 + t;
        const int kc = item >> 6, lane = item & 63;
        const int quad = lane >> 4, nl = lane & 15;
        const float* ep = emb + (size_t)(nsub * 16 + nl) * Dd + kc * 32 + quad * 8;
        const float4 a = *(const float4*)ep;
        const float4 b4 = *(const float4*)(ep + 4);
        const float v[8] = {a.x, a.y, a.z, a.w, b4.x, b4.y, b4.z, b4.w};
        u16x8 hi, lo;
        #pragma unroll
        for (int j = 0; j < 8; ++j) {
            const unsigned short h = f2bf(v[j]);
            hi[j] = h;
            lo[j] = f2bf(v[j] - bf2f(h));
        }
        const size_t off = ((size_t)(nsub * 8 + kc) * 64 + lane) * 8;
        *(u16x8*)&ehg[off] = hi;
        *(u16x8*)&elg[off] = lo;
    }
    // esq: rows nl = t>>4, 16 lanes per row sum 16 ch each
    {
        const int nl = t >> 4, seg = t & 15;
        const float* ep = emb + (size_t)(nsub * 16 + nl) * Dd + seg * 16;
        float s = 0.0f;
        #pragma unroll
        for (int j = 0; j < 4; ++j) {
            const float4 v4 = *(const float4*)(ep + j * 4);
            s += v4.x * v4.x + v4.y * v4.y + v4.z * v4.z + v4.w * v4.w;
        }
        #pragma unroll
        for (int d = 1; d < 16; d <<= 1) s += __shfl_xor(s, d);
        if (seg == 0) esq[nsub * 16 + nl] = s;
    }
}

// ---------------------------------------------------------------------------
// Kernel 2: transpose z [32,256,1024] -> zf [32768, 256].
__global__ __launch_bounds__(256) void transpose_kernel(
        const float* __restrict__ z, float* __restrict__ zf) {
    __shared__ float tile[64][65];
    const int bid = blockIdx.x;
    const int b  = bid >> 6;
    const int ct = (bid >> 4) & 3;
    const int ht = bid & 15;
    const int c0 = ct * 64, hw0 = ht * 64;
    const int t = threadIdx.x;
    const int g  = t & 15;
    const int r0 = t >> 4;
    const size_t zb = (size_t)b * 262144;

    #pragma unroll
    for (int r = 0; r < 4; ++r) {
        const int c_l = r * 16 + r0;
        const float4 v = *(const float4*)(z + zb + (size_t)(c0 + c_l) * 1024 + hw0 + g * 4);
        tile[c_l][g * 4 + 0] = v.x; tile[c_l][g * 4 + 1] = v.y;
        tile[c_l][g * 4 + 2] = v.z; tile[c_l][g * 4 + 3] = v.w;
    }
    __syncthreads();
    #pragma unroll
    for (int r = 0; r < 4; ++r) {
        const int hw_l = r * 16 + r0;
        float4 v;
        v.x = tile[g * 4 + 0][hw_l]; v.y = tile[g * 4 + 1][hw_l];
        v.z = tile[g * 4 + 2][hw_l]; v.w = tile[g * 4 + 3][hw_l];
        *(float4*)(zf + ((size_t)b * 1024 + hw0 + hw_l) * 256 + c0 + g * 4) = v;
    }
}

// ---------------------------------------------------------------------------
// Kernel 3: MFMA distance + full argmin/top-2 per block. 512 blocks, each
// owns 64 points x ALL 1024 codes. z split to LDS bf16 hi/lo ONCE (XOR-
// swizzled chunks -> bank-uniform b128), e fragments direct from global
// (pre-split, L2-hot). In-lane running top-2; one butterfly at the end;
// cross-wave merge in LDS; block writes idx directly + histogram + flags.
__global__ __launch_bounds__(256) void dist_kernel(
        const float* __restrict__ z, const unsigned short* __restrict__ ehg,
        const unsigned short* __restrict__ elg, const float* __restrict__ esq,
        int* __restrict__ idx_i, float* __restrict__ idx_f,
        int* __restrict__ hist_g, int* __restrict__ flagcnt,
        int* __restrict__ flaglist) {
    __shared__ unsigned short zh[64 * 256];  // [m][swizzled chunk*8 + j]
    __shared__ unsigned short zl[64 * 256];
    __shared__ ull mb[4][64], ms[4][64];

    const int t = threadIdx.x, w = t >> 6, L = t & 63;
    const int quad = L >> 4, lr = L & 15;
    const int m0 = blockIdx.x * 64;
    const int b = m0 >> 10, hw0 = m0 & 1023;

    // ---- stage: split z tile once. thread t: m = t&63, c-range (t>>6)*64..+64
    {
        const int ml = t & 63;
        const int c0 = (t >> 6) * 64;
        const float* zp = z + (size_t)b * 262144 + hw0 + ml;
        #pragma unroll
        for (int cg = 0; cg < 8; ++cg) {
            float v[8];
            #pragma unroll
            for (int j = 0; j < 8; ++j)
                v[j] = zp[(size_t)(c0 + cg * 8 + j) * 1024];
            u16x8 hi, lo;
            #pragma unroll
            for (int j = 0; j < 8; ++j) {
                const unsigned short h = f2bf(v[j]);
                hi[j] = h;
                lo[j] = f2bf(v[j] - bf2f(h));
            }
            const int chunk = ((c0 >> 3) + cg) ^ (ml & 7);
            *(u16x8*)&zh[ml * 256 + chunk * 8] = hi;
            *(u16x8*)&zl[ml * 256 + chunk * 8] = lo;
        }
    }
    __syncthreads();

    // ---- main: loop all 8 n-tiles; wave's 32-code slice per tile
    ull bb[16], ss[16];
    #pragma unroll
    for (int i = 0; i < 16; ++i) { bb[i] = ~0ull; ss[i] = ~0ull; }

    for (int nt = 0; nt < 8; ++nt) {
        const int nbase = nt * 128 + w * 32;
        f32x4 acc[4][2];
        #pragma unroll
        for (int mi = 0; mi < 4; ++mi)
            #pragma unroll
            for (int ni = 0; ni < 2; ++ni) acc[mi][ni] = (f32x4){0.f, 0.f, 0.f, 0.f};

        for (int kc = 0; kc < 8; ++kc) {
            bf16x8 ah[4], al[4], bh[2], bl[2];
            #pragma unroll
            for (int mi = 0; mi < 4; ++mi) {
                const int m = mi * 16 + lr;
                const int chunk = (kc * 4 + quad) ^ (lr & 7);
                ah[mi] = *(const bf16x8*)&zh[m * 256 + chunk * 8];
                al[mi] = *(const bf16x8*)&zl[m * 256 + chunk * 8];
            }
            #pragma unroll
            for (int ni = 0; ni < 2; ++ni) {
                const size_t off = ((size_t)(((nbase >> 4) + ni) * 8 + kc) * 64 + L) * 8;
                bh[ni] = *(const bf16x8*)&ehg[off];
                bl[ni] = *(const bf16x8*)&elg[off];
            }
            #pragma unroll
            for (int mi = 0; mi < 4; ++mi)
                #pragma unroll
                for (int ni = 0; ni < 2; ++ni) {
                    acc[mi][ni] = __builtin_amdgcn_mfma_f32_16x16x32_bf16(ah[mi], bh[ni], acc[mi][ni], 0, 0, 0);
                    acc[mi][ni] = __builtin_amdgcn_mfma_f32_16x16x32_bf16(ah[mi], bl[ni], acc[mi][ni], 0, 0, 0);
                    acc[mi][ni] = __builtin_amdgcn_mfma_f32_16x16x32_bf16(al[mi], bh[ni], acc[mi][ni], 0, 0, 0);
                }
        }
        // fold this nt's 2 codes/lane into in-lane running top-2
        float esql[2];
        #pragma unroll
        for (int ni = 0; ni < 2; ++ni) esql[ni] = esq[nbase + ni * 16 + lr];
        #pragma unroll
        for (int mi = 0; mi < 4; ++mi)
            #pragma unroll
            for (int reg = 0; reg < 4; ++reg) {
                const int i = mi * 4 + reg;
                #pragma unroll
                for (int ni = 0; ni < 2; ++ni) {
                    const float val = esql[ni] - 2.0f * acc[mi][ni][reg];
                    const unsigned kg = (unsigned)(nbase + ni * 16 + lr);
                    const ull pk = ((ull)mono(__float_as_uint(val)) << 32) | kg;
                    if (pk < bb[i]) { ss[i] = bb[i]; bb[i] = pk; }
                    else if (pk < ss[i]) { ss[i] = pk; }
                }
            }
    }

    // ---- 16-lane butterfly once per (mi,reg), leaders write LDS
    #pragma unroll
    for (int mi = 0; mi < 4; ++mi)
        #pragma unroll
        for (int reg = 0; reg < 4; ++reg) {
            const int i = mi * 4 + reg;
            ull b2 = bb[i], s2 = ss[i];
            #pragma unroll
            for (int d = 1; d < 16; d <<= 1) {
                const ull ob = __shfl_xor(b2, d);
                const ull os = __shfl_xor(s2, d);
                const ull nb = ob < b2 ? ob : b2;
                const ull mx = ob < b2 ? b2 : ob;
                ull ns = os < s2 ? os : s2;
                ns = mx < ns ? mx : ns;
                b2 = nb; s2 = ns;
            }
            if (lr == 0) {
                const int row = mi * 16 + quad * 4 + reg;
                mb[w][row] = b2;
                ms[w][row] = s2;
            }
        }
    __syncthreads();

    // ---- final cross-wave merge + outputs (threads 0..63)
    if (t < 64) {
        ull b2 = mb[0][t], s2 = ms[0][t];
        #pragma unroll
        for (int ww = 1; ww < 4; ++ww) {
            const ull ob = mb[ww][t], os = ms[ww][t];
            const ull nb = ob < b2 ? ob : b2;
            const ull mx = ob < b2 ? b2 : ob;
            ull ns = os < s2 ? os : s2;
            ns = mx < ns ? mx : ns;
            b2 = nb; s2 = ns;
        }
        const int k = (int)(unsigned)(b2 & 0xFFFFFFFFull);
        idx_i[m0 + t] = k;
        idx_f[m0 + t] = (float)k;
        atomicAdd(&hist_g[k], 1);
        const float v1 = unmono((unsigned)(b2 >> 32));
        const float v2 = unmono((unsigned)(s2 >> 32));
        if (v2 - v1 < EPSGAP) {
            const int pos = atomicAdd(flagcnt, 1);
            flaglist[pos] = m0 + t;
        }
    }
}

// ---------------------------------------------------------------------------
// Kernel 4: exact fp32 re-argmin for flagged points (coalesced zf rows);
// patches idx and hist_g.
__global__ __launch_bounds__(256) void fixup_kernel(
        const float* __restrict__ zf, const float* __restrict__ emb,
        const float* __restrict__ esq, const int* __restrict__ flagcnt,
        const int* __restrict__ flaglist,
        int* __restrict__ idx_i, float* __restrict__ idx_f,
        int* __restrict__ hist_g) {
    __shared__ float zrow[256];
    __shared__ ull red[256];
    const int t = threadIdx.x;
    const int total = flagcnt[0];
    for (int fi = blockIdx.x; fi < total; fi += 64) {
        const int n = flaglist[fi];
        __syncthreads();
        zrow[t] = zf[(size_t)n * Dd + t];
        __syncthreads();
        ull best = ~0ull;
        #pragma unroll
        for (int kc = 0; kc < 4; ++kc) {
            const int k = t * 4 + kc;
            const float* ep = emb + (size_t)k * Dd;
            float dot = 0.0f;
            #pragma unroll 8
            for (int c4 = 0; c4 < 64; ++c4) {
                const float4 e4 = *(const float4*)(ep + c4 * 4);
                const float4 z4 = *(const float4*)&zrow[c4 * 4];
                dot = fmaf(z4.x, e4.x, dot);
                dot = fmaf(z4.y, e4.y, dot);
                dot = fmaf(z4.z, e4.z, dot);
                dot = fmaf(z4.w, e4.w, dot);
            }
            const float val = esq[k] - 2.0f * dot;
            const ull pk = ((ull)mono(__float_as_uint(val)) << 32) | (unsigned)k;
            if (pk < best) best = pk;
        }
        red[t] = best;
        __syncthreads();
        for (int s = 128; s > 0; s >>= 1) {
            if (t < s) { if (red[t + s] < red[t]) red[t] = red[t + s]; }
            __syncthreads();
        }
        if (t == 0) {
            const int knew = (int)(unsigned)(red[0] & 0xFFFFFFFFull);
            const int kold = idx_i[n];
            if (knew != kold) {
                idx_i[n] = knew;
                idx_f[n] = (float)knew;
                atomicSub(&hist_g[kold], 1);
                atomicAdd(&hist_g[knew], 1);
            }
        }
    }
}

// ---------------------------------------------------------------------------
// Kernel 5: scan of hist_g -> counts (float), offsets, cursor. 1 block.
__global__ void scan_kernel(const int* __restrict__ hist_g,
                            float* __restrict__ counts,
                            int* __restrict__ offsets,
                            int* __restrict__ cursor) {
    __shared__ int scan[1024];
    const int t = threadIdx.x;
    const int v = hist_g[t];
    counts[t] = (float)v;
    scan[t] = v;
    __syncthreads();
    for (int s = 1; s < 1024; s <<= 1) {
        const int add = (t >= s) ? scan[t - s] : 0;
        __syncthreads();
        scan[t] += add;
        __syncthreads();
    }
    const int excl = scan[t] - v;
    offsets[t] = excl;
    cursor[t] = excl;
}

// ---------------------------------------------------------------------------
// Kernel 6: counting-sort scatter.
__global__ __launch_bounds__(256) void sort_kernel(
        const int* __restrict__ idx, int* __restrict__ cursor,
        int* __restrict__ sorted, int* __restrict__ codes_sorted) {
    const int n = blockIdx.x * 256 + threadIdx.x;
    const int j = idx[n];
    const int pos = atomicAdd(&cursor[j], 1);
    sorted[pos] = n;
    codes_sorted[pos] = j;
}

// ---------------------------------------------------------------------------
// Kernel 7: balanced segmented reduction -> dw (atomic per segment boundary).
__global__ __launch_bounds__(256) void dw_seg_kernel(
        const float* __restrict__ zf, const int* __restrict__ sorted,
        const int* __restrict__ codes_sorted, float* __restrict__ dw) {
    __shared__ int sid[64];
    __shared__ int scode[65];
    const int t = threadIdx.x;
    const int p0 = blockIdx.x * 64;
    if (t < 64) {
        sid[t] = sorted[p0 + t];
        scode[t] = codes_sorted[p0 + t];
    }
    if (t == 64) scode[64] = -1;
    __syncthreads();
    const int c = t;
    float acc = 0.0f;
    #pragma unroll 8
    for (int p = 0; p < 64; ++p) {
        acc += zf[(size_t)sid[p] * Dd + c];
        if (scode[p] != scode[p + 1]) {
            atomicAdd(&dw[(size_t)scode[p] * Dd + c], acc);
            acc = 0.0f;
        }
    }
}

// ---------------------------------------------------------------------------
// Kernel 8: gather z_q (overwrites zf staging region) + loss partials.
__global__ __launch_bounds__(256) void gather_kernel(
        const float* __restrict__ z, const float* __restrict__ emb,
        const int* __restrict__ idx, float* __restrict__ zq_out,
        float* __restrict__ loss_part) {
    __shared__ float lred[4];
    const int tid = blockIdx.x * 256 + threadIdx.x;
    const int e0 = tid * 4;
    const int c = (e0 >> 10) & 255;
    const int b = e0 >> 18;
    const int n0 = b * 1024 + (e0 & 1023);
    const int4 j4 = *(const int4*)(idx + n0);
    const float4 zv = *(const float4*)(z + e0);
    float4 e;
    e.x = emb[(size_t)j4.x * Dd + c];
    e.y = emb[(size_t)j4.y * Dd + c];
    e.z = emb[(size_t)j4.z * Dd + c];
    e.w = emb[(size_t)j4.w * Dd + c];
    *(float4*)(zq_out + e0) = e;
    const float dx = e.x - zv.x, dy = e.y - zv.y;
    const float dz = e.z - zv.z, dwv = e.w - zv.w;
    float s = dx * dx + dy * dy + dz * dz + dwv * dwv;
    #pragma unroll
    for (int off = 32; off > 0; off >>= 1) s += __shfl_down(s, off);
    if ((threadIdx.x & 63) == 0) lred[threadIdx.x >> 6] = s;
    __syncthreads();
    if (threadIdx.x == 0)
        loss_part[blockIdx.x] = lred[0] + lred[1] + lred[2] + lred[3];
}

// ---------------------------------------------------------------------------
// Kernel 9: cluster-size EMA + Laplace smoothing + loss reduce. 1 block.
__global__ void finalize1_kernel(const float* __restrict__ ema_cs,
                                 const float* __restrict__ counts,
                                 const float* __restrict__ loss_part,
                                 float* __restrict__ cs_out,
                                 float* __restrict__ cs_ws,
                                 float* __restrict__ loss_out) {
    __shared__ float red[1024];
    __shared__ float red2[1024];
    const int k = threadIdx.x;
    const float csr = ema_cs[k] * DECAY + (1.0f - DECAY) * counts[k];
    float lp = 0.0f;
    #pragma unroll
    for (int i = 0; i < 8; ++i) lp += loss_part[i * 1024 + k];
    red[k] = csr;
    red2[k] = lp;
    __syncthreads();
    for (int s = 512; s > 0; s >>= 1) {
        if (k < s) { red[k] += red[k + s]; red2[k] += red2[k + s]; }
        __syncthreads();
    }
    const float nsum = red[0];
    const float cs = (csr + EPSV) / (nsum + (float)Kk * EPSV) * nsum;
    cs_out[k] = cs;
    cs_ws[k] = cs;
    if (k == 0) loss_out[0] = BETA * red2[0] / (float)ZELEM;
}

// ---------------------------------------------------------------------------
// Kernel 10: new_ema_w = EMA(ema_w, dw); new_emb = new_ema_w / cs.
// dw aliases new_emb_out; each thread reads dw[i] then overwrites same i.
__global__ __launch_bounds__(256) void finalize2_kernel(
        const float* __restrict__ ema_w, const float* __restrict__ dw,
        const float* __restrict__ cs_ws,
        float* __restrict__ new_emb_out, float* __restrict__ new_ema_w_out) {
    const int i = blockIdx.x * 256 + threadIdx.x;
    const float nw = ema_w[i] * DECAY + (1.0f - DECAY) * dw[i];
    const float cs = cs_ws[i >> 8];
    new_ema_w_out[i] = nw;
    new_emb_out[i]   = nw / cs;
}

// ---------------------------------------------------------------------------
extern "C" void kernel_launch(void* const* d_in, const int* in_sizes, int n_in,
                              void* d_out, int out_size, void* d_ws, size_t ws_size,
                              hipStream_t stream) {
    const float* z      = (const float*)d_in[0];
    const float* emb    = (const float*)d_in[1];
    const float* ema_cs = (const float*)d_in[2];
    const float* ema_w  = (const float*)d_in[3];

    float* out = (float*)d_out;
    float* zq_out        = out;                 // 8388608 (also zf staging)
    float* idx_out_f     = out + 8388608;       // 32768
    float* loss_out      = out + 8421376;       // 1
    float* new_emb_out   = out + 8421377;       // 262144 (also dw staging)
    float* cs_out        = out + 8683521;       // 1024
    float* new_ema_w_out = out + 8684545;       // 262144

    int*   idx_i    = (int*)d_ws;               // 32768
    int*   sorted   = idx_i + 32768;            // 32768
    int*   codes_s  = sorted + 32768;           // 32768
    int*   offsets  = codes_s + 32768;          // 1024
    int*   cursor   = offsets + 1024;           // 1024
    int*   hist_g   = cursor + 1024;            // 1024
    int*   flagcnt  = hist_g + 1024;            // 1 (+15 pad)
    int*   flaglist = flagcnt + 16;             // 32768
    float* counts   = (float*)(flaglist + 32768);  // 1024
    float* cs_ws    = counts + 1024;            // 1024
    float* esq      = cs_ws + 1024;             // 1024
    float* loss_p   = esq + 1024;               // 8192
    unsigned short* ehg = (unsigned short*)(loss_p + 8192);   // 262144 shorts
    unsigned short* elg = ehg + 262144;                       // 262144 shorts

    float* zf = zq_out;        // transposed z staged in zq output region
    float* dw = new_emb_out;   // dw staged in new_embedding output region

    hipMemsetAsync(dw, 0, (size_t)Kk * Dd * sizeof(float), stream);

    prep_e_kernel<<<64, 256, 0, stream>>>(emb, ehg, elg, esq, hist_g, flagcnt);
    transpose_kernel<<<2048, 256, 0, stream>>>(z, zf);
    dist_kernel<<<Nn / 64, 256, 0, stream>>>(z, ehg, elg, esq, idx_i, idx_out_f,
                                             hist_g, flagcnt, flaglist);
    fixup_kernel<<<64, 256, 0, stream>>>(zf, emb, esq, flagcnt, flaglist,
                                         idx_i, idx_out_f, hist_g);
    scan_kernel<<<1, 1024, 0, stream>>>(hist_g, counts, offsets, cursor);
    sort_kernel<<<Nn / 256, 256, 0, stream>>>(idx_i, cursor, sorted, codes_s);
    dw_seg_kernel<<<Nn / 64, 256, 0, stream>>>(zf, sorted, codes_s, dw);
    gather_kernel<<<ZELEM / 1024, 256, 0, stream>>>(z, emb, idx_i, zq_out, loss_p);
    finalize1_kernel<<<1, 1024, 0, stream>>>(ema_cs, counts, loss_p, cs_out, cs_ws, loss_out);
    finalize2_kernel<<<Kk * Dd / 256, 256, 0, stream>>>(ema_w, dw, cs_ws, new_emb_out, new_ema_w_out);
}

// Round 6
// 311.352 us; speedup vs baseline: 6.7135x; 1.1828x over previous
//
#include <hip/hip_runtime.h>

typedef unsigned long long ull;
typedef __attribute__((ext_vector_type(8))) short bf16x8;
typedef __attribute__((ext_vector_type(4))) float f32x4;
typedef __attribute__((ext_vector_type(8))) unsigned short u16x8;

#define DECAY 0.99f
#define BETA 0.25f
#define EPSV 1e-5f
#define EPSGAP 0.0625f

// z: [32, 256, 32, 32] fp32 ; embedding: [1024, 256] ; N = 32*32*32 = 32768
#define Dd 256
#define Kk 1024
#define Nn 32768
#define ZELEM 8388608

__device__ __forceinline__ unsigned short f2bf(float f) {
    unsigned int x = __float_as_uint(f);
    x += 0x7FFFu + ((x >> 16) & 1u);          // RNE
    return (unsigned short)(x >> 16);
}
__device__ __forceinline__ float bf2f(unsigned short b) {
    return __uint_as_float(((unsigned int)b) << 16);
}
__device__ __forceinline__ unsigned mono(unsigned b) {
    return b ^ (((int)b >> 31) | 0x80000000u);   // monotone float->uint
}
__device__ __forceinline__ float unmono(unsigned m) {
    unsigned b = (m & 0x80000000u) ? (m ^ 0x80000000u) : ~m;
    return __uint_as_float(b);
}
__device__ __forceinline__ unsigned umin32(unsigned a, unsigned b) { return a < b ? a : b; }
__device__ __forceinline__ unsigned umax32(unsigned a, unsigned b) { return a > b ? a : b; }

// ---------------------------------------------------------------------------
// Kernel 1: pre-split embedding into MFMA-B-fragment order (hi/lo bf16),
// compute esq; zero hist / flagcnt / loss_fix / dw. 64 blocks.
__global__ __launch_bounds__(256) void prep_e_kernel(
        const float* __restrict__ emb, unsigned short* __restrict__ ehg,
        unsigned short* __restrict__ elg, float* __restrict__ esq,
        int* __restrict__ hist, int* __restrict__ flagcnt,
        float* __restrict__ loss_fix, float* __restrict__ dw) {
    const int nsub = blockIdx.x;
    const int t = threadIdx.x;
    if (t < 16) hist[nsub * 16 + t] = 0;
    if (nsub == 0 && t == 16) flagcnt[0] = 0;
    if (nsub == 0 && t == 17) loss_fix[0] = 0.0f;
    {
        float4* dwp = (float4*)dw;
        #pragma unroll
        for (int j = 0; j < 4; ++j)
            dwp[(size_t)(nsub * 256 + t) * 4 + j] = make_float4(0.f, 0.f, 0.f, 0.f);
    }
    #pragma unroll
    for (int it = 0; it < 2; ++it) {
        const int item = it * 256 + t;
        const int kc = item >> 6, lane = item & 63;
        const int quad = lane >> 4, nl = lane & 15;
        const float* ep = emb + (size_t)(nsub * 16 + nl) * Dd + kc * 32 + quad * 8;
        const float4 a = *(const float4*)ep;
        const float4 b4 = *(const float4*)(ep + 4);
        const float v[8] = {a.x, a.y, a.z, a.w, b4.x, b4.y, b4.z, b4.w};
        u16x8 hi, lo;
        #pragma unroll
        for (int j = 0; j < 8; ++j) {
            const unsigned short h = f2bf(v[j]);
            hi[j] = h;
            lo[j] = f2bf(v[j] - bf2f(h));
        }
        const size_t off = ((size_t)(nsub * 8 + kc) * 64 + lane) * 8;
        *(u16x8*)&ehg[off] = hi;
        *(u16x8*)&elg[off] = lo;
    }
    {
        const int nl = t >> 4, seg = t & 15;
        const float* ep = emb + (size_t)(nsub * 16 + nl) * Dd + seg * 16;
        float s = 0.0f;
        #pragma unroll
        for (int j = 0; j < 4; ++j) {
            const float4 v4 = *(const float4*)(ep + j * 4);
            s += v4.x * v4.x + v4.y * v4.y + v4.z * v4.z + v4.w * v4.w;
        }
        #pragma unroll
        for (int d = 1; d < 16; d <<= 1) s += __shfl_xor(s, d);
        if (seg == 0) esq[nsub * 16 + nl] = s;
    }
}

// ---------------------------------------------------------------------------
// Kernel 2: fused MFMA distance + top-2 argmin + zf write + hist + loss.
// 512 blocks x 64 points x all 1024 codes; 3-pass bf16 error-corrected GEMM.
// In-lane top-2 as packed u32: bits(val+512) & ~63 | q (6-bit code column).
__global__ __launch_bounds__(256, 2) void dist_kernel(
        const float* __restrict__ z, const unsigned short* __restrict__ ehg,
        const unsigned short* __restrict__ elg, const float* __restrict__ esq,
        float* __restrict__ zf, int* __restrict__ idx_i,
        float* __restrict__ idx_f, int* __restrict__ hist,
        int* __restrict__ flagcnt, int* __restrict__ flaglist,
        float* __restrict__ flagval, float* __restrict__ loss_p) {
    __shared__ __align__(16) unsigned short zh[64 * 256];   // 32KB
    __shared__ __align__(16) unsigned short zl[64 * 256];   // 32KB
    __shared__ ull mb[4][64], ms[4][64];                    // 4KB
    __shared__ float zsqp[256];                             // 1KB

    const int t = threadIdx.x, w = t >> 6, L = t & 63;
    const int quad = L >> 4, lr = L & 15;
    const int m0 = blockIdx.x * 64;
    const int b = m0 >> 10, hw0 = m0 & 1023;

    // ---- stage: wave w converts channels w*64..+63 for all 64 points
    {
        const int c0 = w * 64;
        const float* zp = z + (size_t)b * 262144 + hw0 + L;
        float s = 0.0f;
        #pragma unroll
        for (int cg = 0; cg < 8; ++cg) {
            float v[8];
            #pragma unroll
            for (int j = 0; j < 8; ++j)
                v[j] = zp[(size_t)(c0 + cg * 8 + j) * 1024];
            u16x8 hi, lo;
            #pragma unroll
            for (int j = 0; j < 8; ++j) {
                s = fmaf(v[j], v[j], s);
                const unsigned short h = f2bf(v[j]);
                hi[j] = h;
                lo[j] = f2bf(v[j] - bf2f(h));
            }
            const int chunk = ((c0 >> 3) + cg) ^ (L & 7);
            *(u16x8*)&zh[L * 256 + chunk * 8] = hi;
            *(u16x8*)&zl[L * 256 + chunk * 8] = lo;
        }
        zsqp[L * 4 + w] = s;
    }
    __syncthreads();

    const unsigned short* ehw = ehg + (size_t)(w * 1024 + L) * 8;
    const unsigned short* elw = elg + (size_t)(w * 1024 + L) * 8;

    unsigned bb[16], ss[16];
    #pragma unroll
    for (int i = 0; i < 16; ++i) { bb[i] = 0xFFFFFFFFu; ss[i] = 0xFFFFFFFFu; }

    bf16x8 Bh[2][2], Bl[2][2];
    #pragma unroll
    for (int ni = 0; ni < 2; ++ni) {
        Bh[0][ni] = *(const bf16x8*)(ehw + (size_t)ni * 4096);
        Bl[0][ni] = *(const bf16x8*)(elw + (size_t)ni * 4096);
    }

    for (int nt = 0; nt < 8; ++nt) {
        f32x4 acc[4][2];
        #pragma unroll
        for (int mi = 0; mi < 4; ++mi)
            #pragma unroll
            for (int ni = 0; ni < 2; ++ni) acc[mi][ni] = (f32x4){0.f, 0.f, 0.f, 0.f};

        #pragma unroll
        for (int kc = 0; kc < 8; ++kc) {
            const int cur = kc & 1, nxt = cur ^ 1;
            const int nkc = (kc + 1) & 7;
            const int nnt = (kc == 7) ? ((nt + 1) & 7) : nt;
            #pragma unroll
            for (int ni = 0; ni < 2; ++ni) {
                const size_t o = (size_t)nnt * 32768 + (size_t)ni * 4096 + (size_t)nkc * 512;
                Bh[nxt][ni] = *(const bf16x8*)(ehw + o);
                Bl[nxt][ni] = *(const bf16x8*)(elw + o);
            }
            bf16x8 ah[4], al[4];
            #pragma unroll
            for (int mi = 0; mi < 4; ++mi) {
                const int chunk = (kc * 4 + quad) ^ (lr & 7);
                const int o = (mi * 16 + lr) * 256 + chunk * 8;
                ah[mi] = *(const bf16x8*)&zh[o];
                al[mi] = *(const bf16x8*)&zl[o];
            }
            #pragma unroll
            for (int mi = 0; mi < 4; ++mi)
                #pragma unroll
                for (int ni = 0; ni < 2; ++ni) {
                    acc[mi][ni] = __builtin_amdgcn_mfma_f32_16x16x32_bf16(ah[mi], Bh[cur][ni], acc[mi][ni], 0, 0, 0);
                    acc[mi][ni] = __builtin_amdgcn_mfma_f32_16x16x32_bf16(ah[mi], Bl[cur][ni], acc[mi][ni], 0, 0, 0);
                    acc[mi][ni] = __builtin_amdgcn_mfma_f32_16x16x32_bf16(al[mi], Bh[cur][ni], acc[mi][ni], 0, 0, 0);
                }
        }
        const int q0 = nt * 8 + w * 2;
        const float e0b = esq[q0 * 16 + lr] + 512.0f;
        const float e1b = esq[(q0 + 1) * 16 + lr] + 512.0f;
        #pragma unroll
        for (int mi = 0; mi < 4; ++mi)
            #pragma unroll
            for (int reg = 0; reg < 4; ++reg) {
                const int i = mi * 4 + reg;
                #pragma unroll
                for (int ni = 0; ni < 2; ++ni) {
                    const float val = fmaf(-2.0f, acc[mi][ni][reg], ni ? e1b : e0b);
                    const unsigned pk = (__float_as_uint(val) & 0xFFFFFFC0u) | (unsigned)(q0 + ni);
                    const unsigned mx = umax32(bb[i], pk);
                    bb[i] = umin32(bb[i], pk);
                    ss[i] = umin32(ss[i], mx);
                }
            }
    }

    #pragma unroll
    for (int mi = 0; mi < 4; ++mi)
        #pragma unroll
        for (int reg = 0; reg < 4; ++reg) {
            const int i = mi * 4 + reg;
            ull b2 = ((ull)(bb[i] & 0xFFFFFFC0u) << 14) | (ull)((bb[i] & 63u) * 16 + lr);
            ull s2 = ((ull)(ss[i] & 0xFFFFFFC0u) << 14) | (ull)((ss[i] & 63u) * 16 + lr);
            #pragma unroll
            for (int d = 1; d < 16; d <<= 1) {
                const ull ob = __shfl_xor(b2, d);
                const ull os = __shfl_xor(s2, d);
                const ull mx = ob < b2 ? b2 : ob;
                b2 = ob < b2 ? ob : b2;
                const ull ns = os < s2 ? os : s2;
                s2 = mx < ns ? mx : ns;
            }
            if (lr == 0) {
                const int row = mi * 16 + quad * 4 + reg;
                mb[w][row] = b2;
                ms[w][row] = s2;
            }
        }

    // ---- write zf (reconstructed fp32) from LDS, coalesced 1KB rows
    #pragma unroll
    for (int r = 0; r < 16; ++r) {
        const int m = w * 16 + r;
        const int chunk = (L >> 1) ^ (m & 7);
        const int off = m * 256 + chunk * 8 + (L & 1) * 4;
        const ushort4 h4 = *(const ushort4*)&zh[off];
        const ushort4 l4 = *(const ushort4*)&zl[off];
        float4 o;
        o.x = bf2f(h4.x) + bf2f(l4.x);
        o.y = bf2f(h4.y) + bf2f(l4.y);
        o.z = bf2f(h4.z) + bf2f(l4.z);
        o.w = bf2f(h4.w) + bf2f(l4.w);
        *(float4*)(zf + (size_t)(m0 + m) * 256 + L * 4) = o;
    }
    __syncthreads();

    if (t < 64) {
        ull b2 = mb[0][t], s2 = ms[0][t];
        #pragma unroll
        for (int ww = 1; ww < 4; ++ww) {
            const ull ob = mb[ww][t], os = ms[ww][t];
            const ull mx = ob < b2 ? b2 : ob;
            b2 = ob < b2 ? ob : b2;
            const ull ns = os < s2 ? os : s2;
            s2 = mx < ns ? mx : ns;
        }
        const int k = (int)(b2 & 16383ull);
        const float v1 = __uint_as_float((unsigned)(b2 >> 14)) - 512.0f;
        const float v2 = __uint_as_float((unsigned)(s2 >> 14)) - 512.0f;
        idx_i[m0 + t] = k;
        idx_f[m0 + t] = (float)k;
        atomicAdd(&hist[k], 1);
        if (v2 - v1 < EPSGAP) {
            const int pos = atomicAdd(flagcnt, 1);
            flaglist[pos] = m0 + t;
            flagval[pos] = v1;
        }
        float lp = v1 + zsqp[t * 4] + zsqp[t * 4 + 1] + zsqp[t * 4 + 2] + zsqp[t * 4 + 3];
        #pragma unroll
        for (int d = 32; d > 0; d >>= 1) lp += __shfl_down(lp, d);
        if (t == 0) loss_p[blockIdx.x] = lp;
    }
}

// ---------------------------------------------------------------------------
// Kernel 3: exact fp32 re-argmin for flagged points; patches idx/hist/loss.
__global__ __launch_bounds__(256) void fixup_kernel(
        const float* __restrict__ zf, const float* __restrict__ emb,
        const float* __restrict__ esq, const int* __restrict__ flagcnt,
        const int* __restrict__ flaglist, const float* __restrict__ flagval,
        int* __restrict__ idx_i, float* __restrict__ idx_f,
        int* __restrict__ hist, float* __restrict__ loss_fix) {
    __shared__ float zrow[256];
    __shared__ ull red[256];
    const int t = threadIdx.x;
    const int total = flagcnt[0];
    for (int fi = blockIdx.x; fi < total; fi += 512) {
        const int n = flaglist[fi];
        __syncthreads();
        zrow[t] = zf[(size_t)n * Dd + t];
        __syncthreads();
        ull best = ~0ull;
        #pragma unroll
        for (int kc = 0; kc < 4; ++kc) {
            const int k = t * 4 + kc;
            const float* ep = emb + (size_t)k * Dd;
            float dot = 0.0f;
            #pragma unroll 8
            for (int c4 = 0; c4 < 64; ++c4) {
                const float4 e4 = *(const float4*)(ep + c4 * 4);
                const float4 z4 = *(const float4*)&zrow[c4 * 4];
                dot = fmaf(z4.x, e4.x, dot);
                dot = fmaf(z4.y, e4.y, dot);
                dot = fmaf(z4.z, e4.z, dot);
                dot = fmaf(z4.w, e4.w, dot);
            }
            const float val = esq[k] - 2.0f * dot;
            const ull pk = ((ull)mono(__float_as_uint(val)) << 32) | (unsigned)k;
            if (pk < best) best = pk;
        }
        red[t] = best;
        __syncthreads();
        for (int s = 128; s > 0; s >>= 1) {
            if (t < s) { if (red[t + s] < red[t]) red[t] = red[t + s]; }
            __syncthreads();
        }
        if (t == 0) {
            const int knew = (int)(unsigned)(red[0] & 0xFFFFFFFFull);
            const float vnew = unmono((unsigned)(red[0] >> 32));
            const int kold = idx_i[n];
            if (knew != kold) {
                idx_i[n] = knew;
                idx_f[n] = (float)knew;
                atomicSub(&hist[kold], 1);
                atomicAdd(&hist[knew], 1);
            }
            atomicAdd(loss_fix, vnew - flagval[fi]);
        }
    }
}

// ---------------------------------------------------------------------------
// Kernel 4: exclusive scan of hist -> offsets, cursor. 1 block.
__global__ void scan_kernel(const int* __restrict__ hist,
                            int* __restrict__ offsets,
                            int* __restrict__ cursor) {
    __shared__ int scan[1024];
    const int t = threadIdx.x;
    const int v = hist[t];
    scan[t] = v;
    __syncthreads();
    for (int s = 1; s < 1024; s <<= 1) {
        const int add = (t >= s) ? scan[t - s] : 0;
        __syncthreads();
        scan[t] += add;
        __syncthreads();
    }
    const int excl = scan[t] - v;
    offsets[t] = excl;
    cursor[t] = excl;
}

// ---------------------------------------------------------------------------
// Kernel 5: counting-sort scatter.
__global__ __launch_bounds__(256) void sort_kernel(
        const int* __restrict__ idx, int* __restrict__ cursor,
        int* __restrict__ sorted, int* __restrict__ codes_sorted) {
    const int n = blockIdx.x * 256 + threadIdx.x;
    const int j = idx[n];
    const int pos = atomicAdd(&cursor[j], 1);
    sorted[pos] = n;
    codes_sorted[pos] = j;
}

// ---------------------------------------------------------------------------
// Kernel 6: balanced segmented reduction -> dw (atomic per segment boundary).
__global__ __launch_bounds__(256) void dw_seg_kernel(
        const float* __restrict__ zf, const int* __restrict__ sorted,
        const int* __restrict__ codes_sorted, float* __restrict__ dw) {
    __shared__ int sid[64];
    __shared__ int scode[65];
    const int t = threadIdx.x;
    const int p0 = blockIdx.x * 64;
    if (t < 64) {
        sid[t] = sorted[p0 + t];
        scode[t] = codes_sorted[p0 + t];
    }
    if (t == 64) scode[64] = -1;
    __syncthreads();
    const int c = t;
    float acc = 0.0f;
    #pragma unroll 8
    for (int p = 0; p < 64; ++p) {
        acc += zf[(size_t)sid[p] * Dd + c];
        if (scode[p] != scode[p + 1]) {
            atomicAdd(&dw[(size_t)scode[p] * Dd + c], acc);
            acc = 0.0f;
        }
    }
}

// ---------------------------------------------------------------------------
// Kernel 7: gather z_q (overwrites zf region; runs after fixup/dw_seg).
__global__ __launch_bounds__(256) void gather_kernel(
        const float* __restrict__ emb, const int* __restrict__ idx,
        float* __restrict__ zq_out) {
    const int tid = blockIdx.x * 256 + threadIdx.x;
    const int e0 = tid * 4;
    const int c = (e0 >> 10) & 255;
    const int b = e0 >> 18;
    const int n0 = b * 1024 + (e0 & 1023);
    const int4 j4 = *(const int4*)(idx + n0);
    float4 e;
    e.x = emb[(size_t)j4.x * Dd + c];
    e.y = emb[(size_t)j4.y * Dd + c];
    e.z = emb[(size_t)j4.z * Dd + c];
    e.w = emb[(size_t)j4.w * Dd + c];
    *(float4*)(zq_out + e0) = e;
}

// ---------------------------------------------------------------------------
// Kernel 8: cluster-size EMA + Laplace smoothing + loss reduce. 1 block.
__global__ void finalize1_kernel(const float* __restrict__ ema_cs,
                                 const int* __restrict__ hist,
                                 const float* __restrict__ loss_p,
                                 const float* __restrict__ loss_fix,
                                 float* __restrict__ cs_out,
                                 float* __restrict__ loss_out) {
    __shared__ float red[1024];
    __shared__ float red2[1024];
    const int k = threadIdx.x;
    const float csr = ema_cs[k] * DECAY + (1.0f - DECAY) * (float)hist[k];
    red[k] = csr;
    red2[k] = (k < 512) ? loss_p[k] : 0.0f;
    __syncthreads();
    for (int s = 512; s > 0; s >>= 1) {
        if (k < s) { red[k] += red[k + s]; red2[k] += red2[k + s]; }
        __syncthreads();
    }
    const float nsum = red[0];
    const float cs = (csr + EPSV) / (nsum + (float)Kk * EPSV) * nsum;
    cs_out[k] = cs;
    if (k == 0) loss_out[0] = BETA * (red2[0] + loss_fix[0]) / (float)ZELEM;
}

// ---------------------------------------------------------------------------
// Kernel 9: new_ema_w = EMA(ema_w, dw); new_emb = new_ema_w / cs.
// dw aliases new_emb_out; each thread reads dw[i] then overwrites same i.
__global__ __launch_bounds__(256) void finalize2_kernel(
        const float* __restrict__ ema_w, const float* __restrict__ dw,
        const float* __restrict__ cs_out,
        float* __restrict__ new_emb_out, float* __restrict__ new_ema_w_out) {
    const int i = blockIdx.x * 256 + threadIdx.x;
    const float nw = ema_w[i] * DECAY + (1.0f - DECAY) * dw[i];
    const float cs = cs_out[i >> 8];
    new_ema_w_out[i] = nw;
    new_emb_out[i]   = nw / cs;
}

// ---------------------------------------------------------------------------
extern "C" void kernel_launch(void* const* d_in, const int* in_sizes, int n_in,
                              void* d_out, int out_size, void* d_ws, size_t ws_size,
                              hipStream_t stream) {
    const float* z      = (const float*)d_in[0];
    const float* emb    = (const float*)d_in[1];
    const float* ema_cs = (const float*)d_in[2];
    const float* ema_w  = (const float*)d_in[3];

    float* out = (float*)d_out;
    float* zq_out        = out;                 // 8388608 (zf staging until gather)
    float* idx_out_f     = out + 8388608;       // 32768
    float* loss_out      = out + 8421376;       // 1
    float* new_emb_out   = out + 8421377;       // 262144 (dw staging)
    float* cs_out        = out + 8683521;       // 1024
    float* new_ema_w_out = out + 8684545;       // 262144

    int*   idx_i    = (int*)d_ws;                    // 32768
    int*   sorted   = idx_i + 32768;                 // 32768
    int*   codes_s  = sorted + 32768;                // 32768
    int*   offsets  = codes_s + 32768;               // 1024
    int*   cursor   = offsets + 1024;                // 1024
    int*   hist     = cursor + 1024;                 // 1024
    int*   flagcnt  = hist + 1024;                   // 16
    float* loss_fix = (float*)(flagcnt + 16);        // 16
    int*   flaglist = (int*)(loss_fix + 16);         // 32768
    float* flagval  = (float*)(flaglist + 32768);    // 32768
    float* esq      = flagval + 32768;               // 1024
    float* loss_p   = esq + 1024;                    // 512
    unsigned short* ehg = (unsigned short*)(loss_p + 512);  // 262144 shorts
    unsigned short* elg = ehg + 262144;                     // 262144 shorts

    float* zf = zq_out;        // transposed z staged in zq output region
    float* dw = new_emb_out;   // dw staged in new_embedding output region

    prep_e_kernel<<<64, 256, 0, stream>>>(emb, ehg, elg, esq, hist, flagcnt,
                                          loss_fix, dw);
    dist_kernel<<<Nn / 64, 256, 0, stream>>>(z, ehg, elg, esq, zf, idx_i,
                                             idx_out_f, hist, flagcnt,
                                             flaglist, flagval, loss_p);
    fixup_kernel<<<512, 256, 0, stream>>>(zf, emb, esq, flagcnt, flaglist,
                                          flagval, idx_i, idx_out_f, hist,
                                          loss_fix);
    scan_kernel<<<1, 1024, 0, stream>>>(hist, offsets, cursor);
    sort_kernel<<<Nn / 256, 256, 0, stream>>>(idx_i, cursor, sorted, codes_s);
    dw_seg_kernel<<<Nn / 64, 256, 0, stream>>>(zf, sorted, codes_s, dw);
    gather_kernel<<<ZELEM / 1024, 256, 0, stream>>>(emb, idx_i, zq_out);
    finalize1_kernel<<<1, 1024, 0, stream>>>(ema_cs, hist, loss_p, loss_fix,
                                             cs_out, loss_out);
    finalize2_kernel<<<Kk * Dd / 256, 256, 0, stream>>>(ema_w, dw, cs_out,
                                                        new_emb_out, new_ema_w_out);
}